// Round 5
// baseline (934.968 us; speedup 1.0000x reference)
//
#include <hip/hip_runtime.h>
#include <hip/hip_bf16.h>

#define CUT 10
#define NB 256
#define NLAYERS 4
#define WSTRIDE 48

// slot map (each slot = padded 10x10 complex, 100 float2)
#define SLOT_S0 0
#define SLOT_DM 1      // 1024 displacement-prep matrices
#define SLOT_SQ 1025   // 16 squeezers (l*4+m)
#define SLOT_DS 1041   // 16 displacements (l*4+m)
#define SLOT_BS 1057   // 48 gates * 19 photon-number blocks
#define NSLOTS  1969

typedef __hip_bfloat16 bf16;

// physical (bank-swizzled) per-mode strides: ph = 1110*n0 + 111*n1 + 11*n2 + n3
// (= e + e/10 + e/100; linear in digits so all gate addressing stays strided)
#define F0 1110
#define F1 111
#define F2 11
#define F3 1
#define ST_PHYS 11100   // 9*(1110+111+11+1)+1 = 11098, padded

// read element i of a buffer whose dtype (f32 vs bf16) was sniffed at runtime
__device__ __forceinline__ float readv(const void* p, int i, int isf32) {
  if (isf32) return ((const float*)p)[i];
  return __bfloat162float(((const bf16*)p)[i]);
}

// chunk permutation: wave w handles chunks g_perm[w][0..2]; chunk c = photon
// number N=c/2, spec offset (c&1)*64. Hand-balanced so per-wave sum(d^2) is
// ~84 (range 76..100) -> minimal barrier imbalance.
__device__ const signed char g_perm[16][3] = {
  {18,-1,-1},{19,-1,-1},{16, 0,-1},{17, 1,-1},{20,36,-1},{21,37,-1},
  {14, 6,34},{15, 7,35},{22,30,-1},{23,31,-1},{12, 8, 4},{13, 9, 5},
  {24,28,32},{25,29,33},{10,26, 2},{11,27, 3}
};

// BS pair tables (physical strides), pair order (0,1),(0,2),(0,3),(1,2),(1,3),(2,3)
__device__ const int c_sI[6]   = {F0,F0,F0,F1,F1,F2};
__device__ const int c_sJ[6]   = {F1,F2,F3,F2,F3,F3};
__device__ const int c_sA[6]   = {F2,F1,F1,F0,F0,F0};   // slow spectator (hi digit)
__device__ const int c_sB[6]   = {F3,F3,F2,F3,F2,F1};   // fast spectator (lo digit)
// single-mode gate tables: gate mode m, spectators ascending
__device__ const int c_sM[4]   = {F0,F1,F2,F3};
__device__ const int c_pA[4]   = {F1,F0,F0,F0};
__device__ const int c_pB[4]   = {F2,F2,F1,F1};
__device__ const int c_pC[4]   = {F3,F3,F3,F2};

// ------------------- K0: sniff input dtype -------------------
__global__ void sniff_dtype(const void* p, int n_elems, int* flag) {
  __shared__ float red[256];
  const unsigned short* h = (const unsigned short*)p;
  int t = threadIdx.x;
  float mx = 0.f;
  for (int i = t; i < n_elems; i += 256) {
    unsigned short u = h[i];
    bf16 bv = *(const bf16*)&u;
    float v = fabsf(__bfloat162float(bv));
    if (!(v < 1e30f)) v = 1e30f;
    mx = fmaxf(mx, v);
  }
  red[t] = mx;
  __syncthreads();
  for (int off = 128; off > 0; off >>= 1) {
    if (t < off) red[t] = fmaxf(red[t], red[t + off]);
    __syncthreads();
  }
  if (t == 0) *flag = (red[0] > 1000.f) ? 1 : 0;  // 1 => buffer is really f32
}

// ------------------- K1: build all generators -------------------
__global__ void build_gens(float2* slots, const void* inp, const void* w,
                           const int* flag) {
  int s = blockIdx.x;
  int t = threadIdx.x;
  if (t >= 100) return;
  int isf32 = *flag;
  int i = t / 10, j = t % 10;
  float2 val = make_float2(0.f, 0.f);
  if (s == SLOT_S0) {
    if (j == i + 2)      { float c = sqrtf((float)((i+1)*(i+2))); val.y = -0.25f*c; }
    else if (i == j + 2) { float c = sqrtf((float)((j+1)*(j+2))); val.y = -0.25f*c; }
  } else if (s < SLOT_SQ) {
    int k = s - SLOT_DM;
    float r = readv(inp, k, isf32);
    if (i == j + 1)      val.x =  r * sqrtf((float)(j+1));
    else if (j == i + 1) val.x = -r * sqrtf((float)(i+1));
  } else if (s < SLOT_DS) {
    int k = s - SLOT_SQ; int l = k >> 2; int m = k & 3;
    float r = readv(w, l*WSTRIDE + 16 + m, isf32);
    if (j == i + 2)      val.x =  0.5f*r*sqrtf((float)((i+1)*(i+2)));
    else if (i == j + 2) val.x = -0.5f*r*sqrtf((float)((j+1)*(j+2)));
  } else if (s < SLOT_BS) {
    int k = s - SLOT_DS; int l = k >> 2; int m = k & 3;
    float rd = readv(w, l*WSTRIDE + 36 + m, isf32);
    float ph = readv(w, l*WSTRIDE + 40 + m, isf32);
    float ar = rd * cosf(ph), ai = rd * sinf(ph);
    if (i == j + 1)      { float c = sqrtf((float)(j+1)); val.x =  ar*c; val.y = ai*c; }
    else if (j == i + 1) { float c = sqrtf((float)(i+1)); val.x = -ar*c; val.y = ai*c; }
  } else {
    int rel = s - SLOT_BS;
    int g = rel / 19; int N = rel % 19;
    int l = g / 12; int h = (g % 12) / 6; int p = g % 6;
    float th = readv(w, l*WSTRIDE + (h ? 20 : 0) + p, isf32);
    float ph = readv(w, l*WSTRIDE + (h ? 26 : 6) + p, isf32);
    int lo = max(0, N - 9), hi = min(9, N);
    int d = hi - lo + 1;
    if (i < d && j < d) {
      if (i == j + 1) {
        float c = sqrtf((float)((lo + j + 1) * (N - lo - j)));
        val.x = th * cosf(ph) * c; val.y = th * sinf(ph) * c;
      } else if (j == i + 1) {
        float c = sqrtf((float)((lo + i + 1) * (N - lo - i)));
        val.x = -th * cosf(ph) * c; val.y = th * sinf(ph) * c;
      }
    }
  }
  slots[(size_t)s * 100 + t] = val;
}

// ------------------- K2: generic expm (scaling-squaring + Taylor) -------------------
__global__ void expm_all(float2* slots) {
  __shared__ float2 T[100], P[100], R[100];
  __shared__ float rowsum[10];
  __shared__ int sshift;
  int s = blockIdx.x, t = threadIdx.x;
  int i = t / 10, j = t % 10;
  float2* G = slots + (size_t)s * 100;
  if (t < 100) T[t] = G[t];
  __syncthreads();
  if (t < 10) {
    float sum = 0.f;
    for (int c = 0; c < 10; ++c) { float2 z = T[t*10+c]; sum += fabsf(z.x) + fabsf(z.y); }
    rowsum[t] = sum;
  }
  __syncthreads();
  if (t == 0) {
    float nm = 0.f;
    for (int r = 0; r < 10; ++r) nm = fmaxf(nm, rowsum[r]);
    int sc = 0;
    if (!(nm < 1e6f)) sc = 0;
    else if (nm > 0.25f) sc = (int)ceilf(log2f(nm * 4.f));
    sshift = min(max(sc, 0), 40);
  }
  __syncthreads();
  int sh = sshift;
  float scl = ldexpf(1.f, -sh);
  if (t < 100) {
    float2 z = T[t]; z.x *= scl; z.y *= scl;
    T[t] = z; P[t] = z;
    R[t] = make_float2(z.x + (i == j ? 1.f : 0.f), z.y);
  }
  __syncthreads();
  for (int k = 2; k <= 12; ++k) {
    float2 acc = make_float2(0.f, 0.f);
    if (t < 100) {
      for (int c = 0; c < 10; ++c) {
        float2 a = P[i*10+c], b = T[c*10+j];
        acc.x += a.x*b.x - a.y*b.y;
        acc.y += a.x*b.y + a.y*b.x;
      }
      float inv = 1.f / (float)k;
      acc.x *= inv; acc.y *= inv;
    }
    __syncthreads();
    if (t < 100) { P[t] = acc; R[t].x += acc.x; R[t].y += acc.y; }
    __syncthreads();
  }
  for (int q = 0; q < sh; ++q) {
    float2 acc = make_float2(0.f, 0.f);
    if (t < 100) {
      for (int c = 0; c < 10; ++c) {
        float2 a = R[i*10+c], b = R[c*10+j];
        acc.x += a.x*b.x - a.y*b.y;
        acc.y += a.x*b.y + a.y*b.x;
      }
    }
    __syncthreads();
    if (t < 100) R[t] = acc;
    __syncthreads();
  }
  if (t < 100) G[t] = R[t];
}

// fixed-size BS line kernel: load d-line to regs, apply dxd block, opt phase, store
template<int D>
__device__ __forceinline__ void bs_line_apply(
    float2* st, const float2* __restrict__ U,
    int idx0, int step, int fuse, float angb, float dc)
{
  float2 v[D], o[D];
#pragma unroll
  for (int k = 0; k < D; ++k) v[k] = st[idx0 + k*step];
#pragma unroll
  for (int r = 0; r < D; ++r) {
    float2 acc = make_float2(0.f, 0.f);
#pragma unroll
    for (int k = 0; k < D; ++k) {
      float2 u = U[r*10 + k];
      acc.x = fmaf(u.x, v[k].x, fmaf(-u.y, v[k].y, acc.x));
      acc.y = fmaf(u.x, v[k].y, fmaf( u.y, v[k].x, acc.y));
    }
    o[r] = acc;
  }
  if (fuse) {
#pragma unroll
    for (int r = 0; r < D; ++r) {
      float sn, cs; sincosf(angb + dc*(float)r, &sn, &cs);
      float2 z = o[r];
      o[r] = make_float2(z.x*cs - z.y*sn, z.x*sn + z.y*cs);
    }
  }
#pragma unroll
  for (int r = 0; r < D; ++r) st[idx0 + r*step] = o[r];
}

// ------------------- K3: fused circuit — one block per batch, state in LDS -------------------
__global__ __launch_bounds__(1024, 4) void fused_circuit(
    const float2* __restrict__ slots, const void* __restrict__ w,
    const int* __restrict__ flag, float* __restrict__ out)
{
  __shared__ float2 st[ST_PHYS];   // ~89 KB swizzled state
  __shared__ float2 psi[4][10];
  __shared__ float redw[64];
  const int b = blockIdx.x, t = threadIdx.x;
  const int wv = t >> 6, lane = t & 63;
  const int isf32 = *flag;

  // ---- hoisted per-thread BS round data (reused for all 48 BS gates) ----
  int rN[3], rLo[3], rMi[3], rD[3], rHi[3], rLo10[3];
  bool rVal[3];
#pragma unroll
  for (int r = 0; r < 3; ++r) {
    int c = g_perm[wv][r];
    bool v = (c >= 0);
    int N = 0, spec = 0;
    if (v) { N = c >> 1; spec = ((c & 1) << 6) + lane; v = (spec < 100); }
    rVal[r] = v; rN[r] = N;
    int lo = max(0, N - 9);
    rLo[r] = lo; rMi[r] = N - lo; rD[r] = min(9, N) - lo + 1;
    rHi[r] = spec / 10; rLo10[r] = spec % 10;
  }
  // hoisted single-mode line digits
  const bool smv = (t < 1000);
  const int q0 = t / 100, q1 = (t / 10) % 10, q2 = t % 10;

  // ---- initial product state ----
  if (t < 40) {
    int m = t / 10, r = t % 10;
    const float2* Dm = slots + (size_t)(SLOT_DM + b*4 + m) * 100;
    float2 acc = make_float2(0.f, 0.f);
    for (int c = 0; c < 10; ++c) {
      float2 a = Dm[r*10 + c];
      float2 vv = slots[(size_t)c * 10];   // S0 column 0
      acc.x += a.x*vv.x - a.y*vv.y;
      acc.y += a.x*vv.y + a.y*vv.x;
    }
    psi[m][r] = acc;
  }
  __syncthreads();
  for (int e = t; e < 10000; e += 1024) {
    int ph = e + e/10 + e/100;
    float2 z  = psi[0][e/1000];
    float2 w1 = psi[1][(e/100)%10];
    float2 r1 = make_float2(z.x*w1.x - z.y*w1.y, z.x*w1.y + z.y*w1.x);
    float2 w2 = psi[2][(e/10)%10];
    float2 r2 = make_float2(r1.x*w2.x - r1.y*w2.y, r1.x*w2.y + r1.y*w2.x);
    float2 w3 = psi[3][e%10];
    st[ph] = make_float2(r2.x*w3.x - r2.y*w3.y, r2.x*w3.y + r2.y*w3.x);
  }
  __syncthreads();

  // ---- circuit ----
#pragma unroll 1
  for (int l = 0; l < NLAYERS; ++l) {
#pragma unroll 1
    for (int half = 0; half < 2; ++half) {
      // 6 beamsplitters (vph diag fused into p==5 output)
#pragma unroll 1
      for (int p = 0; p < 6; ++p) {
        int g = l*12 + half*6 + p;
        const float2* Ub = slots + (size_t)(SLOT_BS + g*19) * 100;
        const int sI = c_sI[p], sJ = c_sJ[p], sA = c_sA[p], sB = c_sB[p];
        const int step = sI - sJ;
        const int fuse = (p == 5);   // pair (2,3): spectators mode0(hi), mode1(lo)
        float f0=0.f, f1=0.f, f2=0.f, f3=0.f;
        if (fuse) {
          int off = l*WSTRIDE + (half ? 32 : 12);
          f0 = readv(w, off+0, isf32); f1 = readv(w, off+1, isf32);
          f2 = readv(w, off+2, isf32); f3 = readv(w, off+3, isf32);
        }
#pragma unroll 1
        for (int r = 0; r < 3; ++r) {
          if (rVal[r]) {
            const float2* U = Ub + rN[r]*100;
            int idx0 = rHi[r]*sA + rLo10[r]*sB + rLo[r]*sI + rMi[r]*sJ;
            float angb = 0.f, dc = 0.f;
            if (fuse) {
              dc = f2 - f3;
              angb = f0*(float)rHi[r] + f1*(float)rLo10[r]
                   + f3*(float)rN[r] + dc*(float)rLo[r];
            }
            switch (rD[r]) {
              case 1:  bs_line_apply<1>(st, U, idx0, step, fuse, angb, dc); break;
              case 2:  bs_line_apply<2>(st, U, idx0, step, fuse, angb, dc); break;
              case 3:  bs_line_apply<3>(st, U, idx0, step, fuse, angb, dc); break;
              case 4:  bs_line_apply<4>(st, U, idx0, step, fuse, angb, dc); break;
              case 5:  bs_line_apply<5>(st, U, idx0, step, fuse, angb, dc); break;
              case 6:  bs_line_apply<6>(st, U, idx0, step, fuse, angb, dc); break;
              case 7:  bs_line_apply<7>(st, U, idx0, step, fuse, angb, dc); break;
              case 8:  bs_line_apply<8>(st, U, idx0, step, fuse, angb, dc); break;
              case 9:  bs_line_apply<9>(st, U, idx0, step, fuse, angb, dc); break;
              default: bs_line_apply<10>(st, U, idx0, step, fuse, angb, dc); break;
            }
          }
        }
        __syncthreads();
      }
      // 4 single-mode gates (squeeze half 0 / displace half 1, Kerr fused on last)
#pragma unroll 1
      for (int m = 0; m < 4; ++m) {
        int slot = (half == 0) ? (SLOT_SQ + l*4 + m) : (SLOT_DS + l*4 + m);
        const float2* U = slots + (size_t)slot * 100;
        const int sM = c_sM[m], pA = c_pA[m], pB = c_pB[m], pC = c_pC[m];
        const int kerr = (half == 1 && m == 3);  // q0,q1,q2 = n0,n1,n2
        float k0=0.f, k1=0.f, k2=0.f, k3=0.f;
        if (kerr) {
          int off = l*WSTRIDE + 44;
          k0 = readv(w, off+0, isf32); k1 = readv(w, off+1, isf32);
          k2 = readv(w, off+2, isf32); k3 = readv(w, off+3, isf32);
        }
        if (smv) {
          int base = q0*pA + q1*pB + q2*pC;
          float2 v[10], o[10];
#pragma unroll
          for (int k = 0; k < 10; ++k) v[k] = st[base + k*sM];
#pragma unroll
          for (int r2 = 0; r2 < 10; ++r2) {
            float2 acc = make_float2(0.f, 0.f);
#pragma unroll
            for (int k = 0; k < 10; ++k) {
              float2 u = U[r2*10 + k];
              acc.x = fmaf(u.x, v[k].x, fmaf(-u.y, v[k].y, acc.x));
              acc.y = fmaf(u.x, v[k].y, fmaf( u.y, v[k].x, acc.y));
            }
            o[r2] = acc;
          }
          if (kerr) {
            float angb = k0*(float)(q0*q0) + k1*(float)(q1*q1) + k2*(float)(q2*q2);
#pragma unroll
            for (int r2 = 0; r2 < 10; ++r2) {
              float sn, cs; sincosf(angb + k3*(float)(r2*r2), &sn, &cs);
              float2 z = o[r2];
              o[r2] = make_float2(z.x*cs - z.y*sn, z.x*sn + z.y*cs);
            }
          }
#pragma unroll
          for (int r2 = 0; r2 < 10; ++r2) st[base + r2*sM] = o[r2];
        }
        __syncthreads();
      }
    }
  }

  // ---- photon-number expectations (wave shuffle reduce) ----
  float a0 = 0.f, a1 = 0.f, a2 = 0.f, a3 = 0.f;
  for (int e = t; e < 10000; e += 1024) {
    int ph = e + e/10 + e/100;
    float2 z = st[ph];
    float pz = z.x*z.x + z.y*z.y;
    a0 += pz * (float)(e/1000);
    a1 += pz * (float)((e/100)%10);
    a2 += pz * (float)((e/10)%10);
    a3 += pz * (float)(e%10);
  }
  for (int off2 = 32; off2 > 0; off2 >>= 1) {
    a0 += __shfl_down(a0, off2, 64);
    a1 += __shfl_down(a1, off2, 64);
    a2 += __shfl_down(a2, off2, 64);
    a3 += __shfl_down(a3, off2, 64);
  }
  if (lane == 0) {
    redw[wv*4+0] = a0; redw[wv*4+1] = a1;
    redw[wv*4+2] = a2; redw[wv*4+3] = a3;
  }
  __syncthreads();
  if (t < 4) {
    float s = 0.f;
    for (int ww = 0; ww < 16; ++ww) s += redw[ww*4 + t];
    out[b*4 + t] = s;
  }
}

extern "C" void kernel_launch(void* const* d_in, const int* in_sizes, int n_in,
                              void* d_out, int out_size, void* d_ws, size_t ws_size,
                              hipStream_t stream) {
  const void* inp = d_in[0];
  const void* w   = d_in[1];
  float* out = (float*)d_out;           // reference output dtype is float32
  int*    flag  = (int*)d_ws;           // 16-byte header
  float2* slots = (float2*)((char*)d_ws + 16);

  sniff_dtype<<<dim3(1), dim3(256), 0, stream>>>(inp, in_sizes[0], flag);
  build_gens<<<dim3(NSLOTS), dim3(128), 0, stream>>>(slots, inp, w, flag);
  expm_all<<<dim3(NSLOTS), dim3(128), 0, stream>>>(slots);
  fused_circuit<<<dim3(NB), dim3(1024), 0, stream>>>(slots, w, flag, out);
}

// Round 6
// 816.240 us; speedup vs baseline: 1.1455x; 1.1455x over previous
//
#include <hip/hip_runtime.h>
#include <hip/hip_bf16.h>

#define CUT 10
#define NB 256
#define NLAYERS 4
#define WSTRIDE 48

// slot map (each slot = padded 10x10 complex, 100 float2)
#define SLOT_S0 0
#define SLOT_DM 1      // 1024 displacement-prep matrices
#define SLOT_SQ 1025   // 16 squeezers (l*4+m)
#define SLOT_DS 1041   // 16 displacements (l*4+m)
#define SLOT_BS 1057   // 48 gates * 19 photon-number blocks
#define NSLOTS  1969

typedef __hip_bfloat16 bf16;

// physical (bank-swizzled) per-mode strides: ph = 1110*n0 + 111*n1 + 11*n2 + n3
#define F0 1110
#define F1 111
#define F2 11
#define F3 1
#define ST_PHYS 11100

// read element i of a buffer whose dtype (f32 vs bf16) was sniffed at runtime
__device__ __forceinline__ float readv(const void* p, int i, int isf32) {
  if (isf32) return ((const float*)p)[i];
  return __bfloat162float(((const bf16*)p)[i]);
}

// chunk permutation: wave w handles chunks g_perm[w][0..2]; chunk c: N=c/2,
// spec offset (c&1)*64. Balanced so per-wave sum(d^2) is ~84 (range 76..100).
__device__ const signed char g_perm[16][3] = {
  {18,-1,-1},{19,-1,-1},{16, 0,-1},{17, 1,-1},{20,36,-1},{21,37,-1},
  {14, 6,34},{15, 7,35},{22,30,-1},{23,31,-1},{12, 8, 4},{13, 9, 5},
  {24,28,32},{25,29,33},{10,26, 2},{11,27, 3}
};

// BS pair tables (physical strides), pair order (0,1),(0,2),(0,3),(1,2),(1,3),(2,3)
__device__ const int c_sI[6]   = {F0,F0,F0,F1,F1,F2};
__device__ const int c_sJ[6]   = {F1,F2,F3,F2,F3,F3};
__device__ const int c_sA[6]   = {F2,F1,F1,F0,F0,F0};   // slow spectator (hi digit)
__device__ const int c_sB[6]   = {F3,F3,F2,F3,F2,F1};   // fast spectator (lo digit)
// single-mode gate tables: gate mode m, spectators ascending
__device__ const int c_sM[4]   = {F0,F1,F2,F3};
__device__ const int c_pA[4]   = {F1,F0,F0,F0};
__device__ const int c_pB[4]   = {F2,F2,F1,F1};
__device__ const int c_pC[4]   = {F3,F3,F3,F2};

// ------------------- K0: sniff input dtype -------------------
__global__ void sniff_dtype(const void* p, int n_elems, int* flag) {
  __shared__ float red[256];
  const unsigned short* h = (const unsigned short*)p;
  int t = threadIdx.x;
  float mx = 0.f;
  for (int i = t; i < n_elems; i += 256) {
    unsigned short u = h[i];
    bf16 bv = *(const bf16*)&u;
    float v = fabsf(__bfloat162float(bv));
    if (!(v < 1e30f)) v = 1e30f;
    mx = fmaxf(mx, v);
  }
  red[t] = mx;
  __syncthreads();
  for (int off = 128; off > 0; off >>= 1) {
    if (t < off) red[t] = fmaxf(red[t], red[t + off]);
    __syncthreads();
  }
  if (t == 0) *flag = (red[0] > 1000.f) ? 1 : 0;  // 1 => buffer is really f32
}

// ------------------- K1: build all generators -------------------
__global__ void build_gens(float2* slots, const void* inp, const void* w,
                           const int* flag) {
  int s = blockIdx.x;
  int t = threadIdx.x;
  if (t >= 100) return;
  int isf32 = *flag;
  int i = t / 10, j = t % 10;
  float2 val = make_float2(0.f, 0.f);
  if (s == SLOT_S0) {
    if (j == i + 2)      { float c = sqrtf((float)((i+1)*(i+2))); val.y = -0.25f*c; }
    else if (i == j + 2) { float c = sqrtf((float)((j+1)*(j+2))); val.y = -0.25f*c; }
  } else if (s < SLOT_SQ) {
    int k = s - SLOT_DM;
    float r = readv(inp, k, isf32);
    if (i == j + 1)      val.x =  r * sqrtf((float)(j+1));
    else if (j == i + 1) val.x = -r * sqrtf((float)(i+1));
  } else if (s < SLOT_DS) {
    int k = s - SLOT_SQ; int l = k >> 2; int m = k & 3;
    float r = readv(w, l*WSTRIDE + 16 + m, isf32);
    if (j == i + 2)      val.x =  0.5f*r*sqrtf((float)((i+1)*(i+2)));
    else if (i == j + 2) val.x = -0.5f*r*sqrtf((float)((j+1)*(j+2)));
  } else if (s < SLOT_BS) {
    int k = s - SLOT_DS; int l = k >> 2; int m = k & 3;
    float rd = readv(w, l*WSTRIDE + 36 + m, isf32);
    float ph = readv(w, l*WSTRIDE + 40 + m, isf32);
    float ar = rd * cosf(ph), ai = rd * sinf(ph);
    if (i == j + 1)      { float c = sqrtf((float)(j+1)); val.x =  ar*c; val.y = ai*c; }
    else if (j == i + 1) { float c = sqrtf((float)(i+1)); val.x = -ar*c; val.y = ai*c; }
  } else {
    int rel = s - SLOT_BS;
    int g = rel / 19; int N = rel % 19;
    int l = g / 12; int h = (g % 12) / 6; int p = g % 6;
    float th = readv(w, l*WSTRIDE + (h ? 20 : 0) + p, isf32);
    float ph = readv(w, l*WSTRIDE + (h ? 26 : 6) + p, isf32);
    int lo = max(0, N - 9), hi = min(9, N);
    int d = hi - lo + 1;
    if (i < d && j < d) {
      if (i == j + 1) {
        float c = sqrtf((float)((lo + j + 1) * (N - lo - j)));
        val.x = th * cosf(ph) * c; val.y = th * sinf(ph) * c;
      } else if (j == i + 1) {
        float c = sqrtf((float)((lo + i + 1) * (N - lo - i)));
        val.x = -th * cosf(ph) * c; val.y = th * sinf(ph) * c;
      }
    }
  }
  slots[(size_t)s * 100 + t] = val;
}

// ------------------- K2: generic expm (scaling-squaring + Taylor) -------------------
__global__ void expm_all(float2* slots) {
  __shared__ float2 T[100], P[100], R[100];
  __shared__ float rowsum[10];
  __shared__ int sshift;
  int s = blockIdx.x, t = threadIdx.x;
  int i = t / 10, j = t % 10;
  float2* G = slots + (size_t)s * 100;
  if (t < 100) T[t] = G[t];
  __syncthreads();
  if (t < 10) {
    float sum = 0.f;
    for (int c = 0; c < 10; ++c) { float2 z = T[t*10+c]; sum += fabsf(z.x) + fabsf(z.y); }
    rowsum[t] = sum;
  }
  __syncthreads();
  if (t == 0) {
    float nm = 0.f;
    for (int r = 0; r < 10; ++r) nm = fmaxf(nm, rowsum[r]);
    int sc = 0;
    if (!(nm < 1e6f)) sc = 0;
    else if (nm > 0.25f) sc = (int)ceilf(log2f(nm * 4.f));
    sshift = min(max(sc, 0), 40);
  }
  __syncthreads();
  int sh = sshift;
  float scl = ldexpf(1.f, -sh);
  if (t < 100) {
    float2 z = T[t]; z.x *= scl; z.y *= scl;
    T[t] = z; P[t] = z;
    R[t] = make_float2(z.x + (i == j ? 1.f : 0.f), z.y);
  }
  __syncthreads();
  for (int k = 2; k <= 12; ++k) {
    float2 acc = make_float2(0.f, 0.f);
    if (t < 100) {
      for (int c = 0; c < 10; ++c) {
        float2 a = P[i*10+c], b = T[c*10+j];
        acc.x += a.x*b.x - a.y*b.y;
        acc.y += a.x*b.y + a.y*b.x;
      }
      float inv = 1.f / (float)k;
      acc.x *= inv; acc.y *= inv;
    }
    __syncthreads();
    if (t < 100) { P[t] = acc; R[t].x += acc.x; R[t].y += acc.y; }
    __syncthreads();
  }
  for (int q = 0; q < sh; ++q) {
    float2 acc = make_float2(0.f, 0.f);
    if (t < 100) {
      for (int c = 0; c < 10; ++c) {
        float2 a = R[i*10+c], b = R[c*10+j];
        acc.x += a.x*b.x - a.y*b.y;
        acc.y += a.x*b.y + a.y*b.x;
      }
    }
    __syncthreads();
    if (t < 100) R[t] = acc;
    __syncthreads();
  }
  if (t < 100) G[t] = R[t];
}

// ------------------- K3: fused circuit — one block per batch, state in LDS -------------------
__global__ __launch_bounds__(1024) void fused_circuit(
    const float2* __restrict__ slots, const void* __restrict__ w,
    const int* __restrict__ flag, float* __restrict__ out)
{
  __shared__ float2 st[ST_PHYS];   // ~89 KB swizzled state
  __shared__ float2 psi[4][10];
  __shared__ float redw[64];
  const int b = blockIdx.x, t = threadIdx.x;
  const int wv = t >> 6, lane = t & 63;
  const int isf32 = *flag;

  // ---- hoisted per-thread BS chunk data; ONLY accessed at compile-time
  // indices (fully unrolled loops) so SROA keeps it in registers ----
  int chVal[3], chN[3], chLo[3], chMi[3], chD[3], chHi[3], chLo10[3];
#pragma unroll
  for (int r = 0; r < 3; ++r) {
    int c = g_perm[wv][r];
    int v = (c >= 0);
    int N = v ? (c >> 1) : 0;
    int spec = ((c & 1) << 6) + lane;
    v = v && (spec < 100);
    int lo = max(0, N - 9);
    chVal[r] = v; chN[r] = N; chLo[r] = lo; chMi[r] = N - lo;
    chD[r] = min(9, N) - lo + 1;
    chHi[r] = spec / 10; chLo10[r] = spec % 10;
  }
  const bool smv = (t < 1000);
  const int q0 = t / 100, q1 = (t / 10) % 10, q2 = t % 10;

  // ---- initial product state ----
  if (t < 40) {
    int m = t / 10, r = t % 10;
    const float2* Dm = slots + (size_t)(SLOT_DM + b*4 + m) * 100;
    float2 acc = make_float2(0.f, 0.f);
    for (int c = 0; c < 10; ++c) {
      float2 a = Dm[r*10 + c];
      float2 vv = slots[(size_t)c * 10];   // S0 column 0
      acc.x += a.x*vv.x - a.y*vv.y;
      acc.y += a.x*vv.y + a.y*vv.x;
    }
    psi[m][r] = acc;
  }
  __syncthreads();
  for (int e = t; e < 10000; e += 1024) {
    int ph = e + e/10 + e/100;
    float2 z  = psi[0][e/1000];
    float2 w1 = psi[1][(e/100)%10];
    float2 r1 = make_float2(z.x*w1.x - z.y*w1.y, z.x*w1.y + z.y*w1.x);
    float2 w2 = psi[2][(e/10)%10];
    float2 r2 = make_float2(r1.x*w2.x - r1.y*w2.y, r1.x*w2.y + r1.y*w2.x);
    float2 w3 = psi[3][e%10];
    st[ph] = make_float2(r2.x*w3.x - r2.y*w3.y, r2.x*w3.y + r2.y*w3.x);
  }
  __syncthreads();

  // ---- circuit ----
#pragma unroll 1
  for (int l = 0; l < NLAYERS; ++l) {
#pragma unroll 1
    for (int half = 0; half < 2; ++half) {
      // 6 beamsplitters (vph diag fused into p==5 output)
#pragma unroll 1
      for (int p = 0; p < 6; ++p) {
        int g = l*12 + half*6 + p;
        const float2* Ub = slots + (size_t)(SLOT_BS + g*19) * 100;
        const int sI = c_sI[p], sJ = c_sJ[p], sA = c_sA[p], sB = c_sB[p];
        const int step = sI - sJ;
        const int fuse = (p == 5);   // pair (2,3): spectators mode0(hi), mode1(lo)
        float f0=0.f, f1=0.f, fdc=0.f, f3=0.f;
        if (fuse) {
          int off = l*WSTRIDE + (half ? 32 : 12);
          f0 = readv(w, off+0, isf32); f1 = readv(w, off+1, isf32);
          float f2 = readv(w, off+2, isf32); f3 = readv(w, off+3, isf32);
          fdc = f2 - f3;
        }
#pragma unroll
        for (int r = 0; r < 3; ++r) {
          if (chVal[r]) {
            // d is wave-uniform (chunk = single N) -> scalar loop bound:
            // unrolled iterations beyond sd are s_cbranch-skipped, not masked
            const int sd = __builtin_amdgcn_readfirstlane(chD[r]);
            const float2* U = Ub + chN[r]*100;
            const int idx0 = chHi[r]*sA + chLo10[r]*sB + chLo[r]*sI + chMi[r]*sJ;
            float2 v[10], o[10];
#pragma unroll
            for (int k = 0; k < 10; ++k) if (k < sd) v[k] = st[idx0 + k*step];
#pragma unroll
            for (int rr = 0; rr < 10; ++rr) if (rr < sd) {
              float2 acc = make_float2(0.f, 0.f);
#pragma unroll
              for (int k = 0; k < 10; ++k) if (k < sd) {
                float2 u = U[rr*10 + k];
                acc.x = fmaf(u.x, v[k].x, fmaf(-u.y, v[k].y, acc.x));
                acc.y = fmaf(u.x, v[k].y, fmaf( u.y, v[k].x, acc.y));
              }
              o[rr] = acc;
            }
            if (fuse) {
              float angb = f0*(float)chHi[r] + f1*(float)chLo10[r]
                         + f3*(float)chN[r] + fdc*(float)chLo[r];
#pragma unroll
              for (int rr = 0; rr < 10; ++rr) if (rr < sd) {
                float sn, cs; sincosf(angb + fdc*(float)rr, &sn, &cs);
                float2 z = o[rr];
                o[rr] = make_float2(z.x*cs - z.y*sn, z.x*sn + z.y*cs);
              }
            }
#pragma unroll
            for (int rr = 0; rr < 10; ++rr) if (rr < sd) st[idx0 + rr*step] = o[rr];
          }
        }
        __syncthreads();
      }
      // 4 single-mode gates (squeeze half 0 / displace half 1, Kerr fused on last)
#pragma unroll 1
      for (int m = 0; m < 4; ++m) {
        int slot = (half == 0) ? (SLOT_SQ + l*4 + m) : (SLOT_DS + l*4 + m);
        const float2* U = slots + (size_t)slot * 100;
        const int sM = c_sM[m], pA = c_pA[m], pB = c_pB[m], pC = c_pC[m];
        const int kerr = (half == 1 && m == 3);  // q0,q1,q2 = n0,n1,n2
        float k0=0.f, k1=0.f, k2=0.f, k3=0.f;
        if (kerr) {
          int off = l*WSTRIDE + 44;
          k0 = readv(w, off+0, isf32); k1 = readv(w, off+1, isf32);
          k2 = readv(w, off+2, isf32); k3 = readv(w, off+3, isf32);
        }
        if (smv) {
          int base = q0*pA + q1*pB + q2*pC;
          float2 v[10], o[10];
#pragma unroll
          for (int k = 0; k < 10; ++k) v[k] = st[base + k*sM];
#pragma unroll
          for (int r2 = 0; r2 < 10; ++r2) {
            float2 acc = make_float2(0.f, 0.f);
#pragma unroll
            for (int k = 0; k < 10; ++k) {
              float2 u = U[r2*10 + k];
              acc.x = fmaf(u.x, v[k].x, fmaf(-u.y, v[k].y, acc.x));
              acc.y = fmaf(u.x, v[k].y, fmaf( u.y, v[k].x, acc.y));
            }
            o[r2] = acc;
          }
          if (kerr) {
            float angb = k0*(float)(q0*q0) + k1*(float)(q1*q1) + k2*(float)(q2*q2);
#pragma unroll
            for (int r2 = 0; r2 < 10; ++r2) {
              float sn, cs; sincosf(angb + k3*(float)(r2*r2), &sn, &cs);
              float2 z = o[r2];
              o[r2] = make_float2(z.x*cs - z.y*sn, z.x*sn + z.y*cs);
            }
          }
#pragma unroll
          for (int r2 = 0; r2 < 10; ++r2) st[base + r2*sM] = o[r2];
        }
        __syncthreads();
      }
    }
  }

  // ---- photon-number expectations (wave shuffle reduce) ----
  float a0 = 0.f, a1 = 0.f, a2 = 0.f, a3 = 0.f;
  for (int e = t; e < 10000; e += 1024) {
    int ph = e + e/10 + e/100;
    float2 z = st[ph];
    float pz = z.x*z.x + z.y*z.y;
    a0 += pz * (float)(e/1000);
    a1 += pz * (float)((e/100)%10);
    a2 += pz * (float)((e/10)%10);
    a3 += pz * (float)(e%10);
  }
  for (int off2 = 32; off2 > 0; off2 >>= 1) {
    a0 += __shfl_down(a0, off2, 64);
    a1 += __shfl_down(a1, off2, 64);
    a2 += __shfl_down(a2, off2, 64);
    a3 += __shfl_down(a3, off2, 64);
  }
  if (lane == 0) {
    redw[wv*4+0] = a0; redw[wv*4+1] = a1;
    redw[wv*4+2] = a2; redw[wv*4+3] = a3;
  }
  __syncthreads();
  if (t < 4) {
    float s = 0.f;
    for (int ww = 0; ww < 16; ++ww) s += redw[ww*4 + t];
    out[b*4 + t] = s;
  }
}

extern "C" void kernel_launch(void* const* d_in, const int* in_sizes, int n_in,
                              void* d_out, int out_size, void* d_ws, size_t ws_size,
                              hipStream_t stream) {
  const void* inp = d_in[0];
  const void* w   = d_in[1];
  float* out = (float*)d_out;           // reference output dtype is float32
  int*    flag  = (int*)d_ws;           // 16-byte header
  float2* slots = (float2*)((char*)d_ws + 16);

  sniff_dtype<<<dim3(1), dim3(256), 0, stream>>>(inp, in_sizes[0], flag);
  build_gens<<<dim3(NSLOTS), dim3(128), 0, stream>>>(slots, inp, w, flag);
  expm_all<<<dim3(NSLOTS), dim3(128), 0, stream>>>(slots);
  fused_circuit<<<dim3(NB), dim3(1024), 0, stream>>>(slots, w, flag, out);
}

// Round 7
// 735.648 us; speedup vs baseline: 1.2709x; 1.1096x over previous
//
#include <hip/hip_runtime.h>
#include <hip/hip_bf16.h>

#define CUT 10
#define NB 256
#define NLAYERS 4
#define WSTRIDE 48

// slot map (each slot = padded 10x10 complex, 100 float2)
#define SLOT_S0 0
#define SLOT_DM 1      // 1024 displacement-prep matrices
#define SLOT_SQ 1025   // 16 squeezers (l*4+m)
#define SLOT_DS 1041   // 16 displacements (l*4+m)
#define SLOT_BS 1057   // 48 gates * 19 photon-number blocks
#define NSLOTS  1969

typedef __hip_bfloat16 bf16;

// physical (bank-swizzled) per-mode strides: ph = 1110*n0 + 111*n1 + 11*n2 + n3
#define F0 1110
#define F1 111
#define F2 11
#define F3 1
#define ST_PHYS 11100

// read element i of a buffer whose dtype (f32 vs bf16) was sniffed at runtime
__device__ __forceinline__ float readv(const void* p, int i, int isf32) {
  if (isf32) return ((const float*)p)[i];
  return __bfloat162float(((const bf16*)p)[i]);
}

// chunk permutation: wave w handles chunks g_perm[w][0..2]; chunk c: N=c/2,
// spec offset (c&1)*64. Balanced so per-wave sum(d^2) is ~84 (range 76..100).
__device__ const signed char g_perm[16][3] = {
  {18,-1,-1},{19,-1,-1},{16, 0,-1},{17, 1,-1},{20,36,-1},{21,37,-1},
  {14, 6,34},{15, 7,35},{22,30,-1},{23,31,-1},{12, 8, 4},{13, 9, 5},
  {24,28,32},{25,29,33},{10,26, 2},{11,27, 3}
};

// BS pair tables (physical strides), pair order (0,1),(0,2),(0,3),(1,2),(1,3),(2,3)
__device__ const int c_sI[6]   = {F0,F0,F0,F1,F1,F2};
__device__ const int c_sJ[6]   = {F1,F2,F3,F2,F3,F3};
__device__ const int c_sA[6]   = {F2,F1,F1,F0,F0,F0};   // slow spectator (hi digit)
__device__ const int c_sB[6]   = {F3,F3,F2,F3,F2,F1};   // fast spectator (lo digit)
// single-mode gate tables: gate mode m, spectators ascending
__device__ const int c_sM[4]   = {F0,F1,F2,F3};
__device__ const int c_pA[4]   = {F1,F0,F0,F0};
__device__ const int c_pB[4]   = {F2,F2,F1,F1};
__device__ const int c_pC[4]   = {F3,F3,F3,F2};

// ------------------- K0: sniff input dtype -------------------
__global__ void sniff_dtype(const void* p, int n_elems, int* flag) {
  __shared__ float red[256];
  const unsigned short* h = (const unsigned short*)p;
  int t = threadIdx.x;
  float mx = 0.f;
  for (int i = t; i < n_elems; i += 256) {
    unsigned short u = h[i];
    bf16 bv = *(const bf16*)&u;
    float v = fabsf(__bfloat162float(bv));
    if (!(v < 1e30f)) v = 1e30f;
    mx = fmaxf(mx, v);
  }
  red[t] = mx;
  __syncthreads();
  for (int off = 128; off > 0; off >>= 1) {
    if (t < off) red[t] = fmaxf(red[t], red[t + off]);
    __syncthreads();
  }
  if (t == 0) *flag = (red[0] > 1000.f) ? 1 : 0;  // 1 => buffer is really f32
}

// ------------------- K1: build all generators -------------------
__global__ void build_gens(float2* slots, const void* inp, const void* w,
                           const int* flag) {
  int s = blockIdx.x;
  int t = threadIdx.x;
  if (t >= 100) return;
  int isf32 = *flag;
  int i = t / 10, j = t % 10;
  float2 val = make_float2(0.f, 0.f);
  if (s == SLOT_S0) {
    if (j == i + 2)      { float c = sqrtf((float)((i+1)*(i+2))); val.y = -0.25f*c; }
    else if (i == j + 2) { float c = sqrtf((float)((j+1)*(j+2))); val.y = -0.25f*c; }
  } else if (s < SLOT_SQ) {
    int k = s - SLOT_DM;
    float r = readv(inp, k, isf32);
    if (i == j + 1)      val.x =  r * sqrtf((float)(j+1));
    else if (j == i + 1) val.x = -r * sqrtf((float)(i+1));
  } else if (s < SLOT_DS) {
    int k = s - SLOT_SQ; int l = k >> 2; int m = k & 3;
    float r = readv(w, l*WSTRIDE + 16 + m, isf32);
    if (j == i + 2)      val.x =  0.5f*r*sqrtf((float)((i+1)*(i+2)));
    else if (i == j + 2) val.x = -0.5f*r*sqrtf((float)((j+1)*(j+2)));
  } else if (s < SLOT_BS) {
    int k = s - SLOT_DS; int l = k >> 2; int m = k & 3;
    float rd = readv(w, l*WSTRIDE + 36 + m, isf32);
    float ph = readv(w, l*WSTRIDE + 40 + m, isf32);
    float ar = rd * cosf(ph), ai = rd * sinf(ph);
    if (i == j + 1)      { float c = sqrtf((float)(j+1)); val.x =  ar*c; val.y = ai*c; }
    else if (j == i + 1) { float c = sqrtf((float)(i+1)); val.x = -ar*c; val.y = ai*c; }
  } else {
    int rel = s - SLOT_BS;
    int g = rel / 19; int N = rel % 19;
    int l = g / 12; int h = (g % 12) / 6; int p = g % 6;
    float th = readv(w, l*WSTRIDE + (h ? 20 : 0) + p, isf32);
    float ph = readv(w, l*WSTRIDE + (h ? 26 : 6) + p, isf32);
    int lo = max(0, N - 9), hi = min(9, N);
    int d = hi - lo + 1;
    if (i < d && j < d) {
      if (i == j + 1) {
        float c = sqrtf((float)((lo + j + 1) * (N - lo - j)));
        val.x = th * cosf(ph) * c; val.y = th * sinf(ph) * c;
      } else if (j == i + 1) {
        float c = sqrtf((float)((lo + i + 1) * (N - lo - i)));
        val.x = -th * cosf(ph) * c; val.y = th * sinf(ph) * c;
      }
    }
  }
  slots[(size_t)s * 100 + t] = val;
}

// ------------------- K2: generic expm (scaling-squaring + Taylor) -------------------
__global__ void expm_all(float2* slots) {
  __shared__ float2 T[100], P[100], R[100];
  __shared__ float rowsum[10];
  __shared__ int sshift;
  int s = blockIdx.x, t = threadIdx.x;
  int i = t / 10, j = t % 10;
  float2* G = slots + (size_t)s * 100;
  if (t < 100) T[t] = G[t];
  __syncthreads();
  if (t < 10) {
    float sum = 0.f;
    for (int c = 0; c < 10; ++c) { float2 z = T[t*10+c]; sum += fabsf(z.x) + fabsf(z.y); }
    rowsum[t] = sum;
  }
  __syncthreads();
  if (t == 0) {
    float nm = 0.f;
    for (int r = 0; r < 10; ++r) nm = fmaxf(nm, rowsum[r]);
    int sc = 0;
    if (!(nm < 1e6f)) sc = 0;
    else if (nm > 0.25f) sc = (int)ceilf(log2f(nm * 4.f));
    sshift = min(max(sc, 0), 40);
  }
  __syncthreads();
  int sh = sshift;
  float scl = ldexpf(1.f, -sh);
  if (t < 100) {
    float2 z = T[t]; z.x *= scl; z.y *= scl;
    T[t] = z; P[t] = z;
    R[t] = make_float2(z.x + (i == j ? 1.f : 0.f), z.y);
  }
  __syncthreads();
  for (int k = 2; k <= 12; ++k) {
    float2 acc = make_float2(0.f, 0.f);
    if (t < 100) {
      for (int c = 0; c < 10; ++c) {
        float2 a = P[i*10+c], b = T[c*10+j];
        acc.x += a.x*b.x - a.y*b.y;
        acc.y += a.x*b.y + a.y*b.x;
      }
      float inv = 1.f / (float)k;
      acc.x *= inv; acc.y *= inv;
    }
    __syncthreads();
    if (t < 100) { P[t] = acc; R[t].x += acc.x; R[t].y += acc.y; }
    __syncthreads();
  }
  for (int q = 0; q < sh; ++q) {
    float2 acc = make_float2(0.f, 0.f);
    if (t < 100) {
      for (int c = 0; c < 10; ++c) {
        float2 a = R[i*10+c], b = R[c*10+j];
        acc.x += a.x*b.x - a.y*b.y;
        acc.y += a.x*b.y + a.y*b.x;
      }
    }
    __syncthreads();
    if (t < 100) R[t] = acc;
    __syncthreads();
  }
  if (t < 100) G[t] = R[t];
}

// ------------------- K3: fused circuit — one block per batch, state in LDS -------------------
// amdgpu_waves_per_eu(4,4): LDS (89.6 KB) already forces 1 block/CU = 4 waves/EU;
// telling the allocator raises the VGPR cap 64 -> 128 and kills scratch spills.
__global__ __launch_bounds__(1024) __attribute__((amdgpu_waves_per_eu(4, 4)))
void fused_circuit(
    const float2* __restrict__ slots, const void* __restrict__ w,
    const int* __restrict__ flag, float* __restrict__ out)
{
  __shared__ float2 st[ST_PHYS];   // ~89 KB swizzled state
  __shared__ float2 psi[4][10];
  __shared__ float redw[64];
  const int b = blockIdx.x, t = threadIdx.x;
  const int wv = t >> 6, lane = t & 63;
  const int isf32 = *flag;

  const bool smv = (t < 1000);
  const int q0 = t / 100, q1 = (t / 10) % 10, q2 = t % 10;

  // ---- initial product state ----
  if (t < 40) {
    int m = t / 10, r = t % 10;
    const float2* Dm = slots + (size_t)(SLOT_DM + b*4 + m) * 100;
    float2 acc = make_float2(0.f, 0.f);
    for (int c = 0; c < 10; ++c) {
      float2 a = Dm[r*10 + c];
      float2 vv = slots[(size_t)c * 10];   // S0 column 0
      acc.x += a.x*vv.x - a.y*vv.y;
      acc.y += a.x*vv.y + a.y*vv.x;
    }
    psi[m][r] = acc;
  }
  __syncthreads();
  for (int e = t; e < 10000; e += 1024) {
    int ph = e + e/10 + e/100;
    float2 z  = psi[0][e/1000];
    float2 w1 = psi[1][(e/100)%10];
    float2 r1 = make_float2(z.x*w1.x - z.y*w1.y, z.x*w1.y + z.y*w1.x);
    float2 w2 = psi[2][(e/10)%10];
    float2 r2 = make_float2(r1.x*w2.x - r1.y*w2.y, r1.x*w2.y + r1.y*w2.x);
    float2 w3 = psi[3][e%10];
    st[ph] = make_float2(r2.x*w3.x - r2.y*w3.y, r2.x*w3.y + r2.y*w3.x);
  }
  __syncthreads();

  // ---- circuit ----
#pragma unroll 1
  for (int l = 0; l < NLAYERS; ++l) {
#pragma unroll 1
    for (int half = 0; half < 2; ++half) {
      // 6 beamsplitters (vph diag fused into p==5 output)
#pragma unroll 1
      for (int p = 0; p < 6; ++p) {
        int g = l*12 + half*6 + p;
        const float2* Ub = slots + (size_t)(SLOT_BS + g*19) * 100;
        const int sI = c_sI[p], sJ = c_sJ[p], sA = c_sA[p], sB = c_sB[p];
        const int step = sI - sJ;
        const int fuse = (p == 5);   // pair (2,3): spectators mode0(hi), mode1(lo)
        float f0=0.f, f1=0.f, fdc=0.f, f3=0.f;
        if (fuse) {
          int off = l*WSTRIDE + (half ? 32 : 12);
          f0 = readv(w, off+0, isf32); f1 = readv(w, off+1, isf32);
          float f2 = readv(w, off+2, isf32); f3 = readv(w, off+3, isf32);
          fdc = f2 - f3;
        }
        // per-slot metadata derived on the fly (wave-uniform scalar part +
        // ~6 VALU for the lane part) -> no persistent registers
#pragma unroll
        for (int r = 0; r < 3; ++r) {
          int c = g_perm[wv][r];
          if (c >= 0) {
            int N = c >> 1;
            int spec = ((c & 1) << 6) + lane;
            if (spec < 100) {
              int lo = max(0, N - 9);
              // d is wave-uniform (chunk = single N) -> scalar loop bound:
              // unrolled iterations beyond sd are s_cbranch-skipped, not masked
              const int sd = __builtin_amdgcn_readfirstlane(min(9, N) - lo + 1);
              int hi10 = spec / 10, lo10 = spec % 10;
              const float2* U = Ub + N*100;
              const int idx0 = hi10*sA + lo10*sB + lo*sI + (N - lo)*sJ;
              float angb = 0.f;
              if (fuse)
                angb = f0*(float)hi10 + f1*(float)lo10
                     + f3*(float)N + fdc*(float)lo;
              float2 v[10];
#pragma unroll
              for (int k = 0; k < 10; ++k) if (k < sd) v[k] = st[idx0 + k*step];
#pragma unroll
              for (int rr = 0; rr < 10; ++rr) if (rr < sd) {
                float2 acc = make_float2(0.f, 0.f);
#pragma unroll
                for (int k = 0; k < 10; ++k) if (k < sd) {
                  float2 u = U[rr*10 + k];
                  acc.x = fmaf(u.x, v[k].x, fmaf(-u.y, v[k].y, acc.x));
                  acc.y = fmaf(u.x, v[k].y, fmaf( u.y, v[k].x, acc.y));
                }
                if (fuse) {
                  float sn, cs; sincosf(angb + fdc*(float)rr, &sn, &cs);
                  acc = make_float2(acc.x*cs - acc.y*sn, acc.x*sn + acc.y*cs);
                }
                st[idx0 + rr*step] = acc;   // v[] is in regs; line is lane-private
              }
            }
          }
        }
        __syncthreads();
      }
      // 4 single-mode gates (squeeze half 0 / displace half 1, Kerr fused on last)
#pragma unroll 1
      for (int m = 0; m < 4; ++m) {
        int slot = (half == 0) ? (SLOT_SQ + l*4 + m) : (SLOT_DS + l*4 + m);
        const float2* U = slots + (size_t)slot * 100;
        const int sM = c_sM[m], pA = c_pA[m], pB = c_pB[m], pC = c_pC[m];
        const int kerr = (half == 1 && m == 3);  // q0,q1,q2 = n0,n1,n2
        float k0=0.f, k1=0.f, k2=0.f, k3=0.f;
        if (kerr) {
          int off = l*WSTRIDE + 44;
          k0 = readv(w, off+0, isf32); k1 = readv(w, off+1, isf32);
          k2 = readv(w, off+2, isf32); k3 = readv(w, off+3, isf32);
        }
        if (smv) {
          int base = q0*pA + q1*pB + q2*pC;
          float angb = 0.f;
          if (kerr) angb = k0*(float)(q0*q0) + k1*(float)(q1*q1) + k2*(float)(q2*q2);
          float2 v[10];
#pragma unroll
          for (int k = 0; k < 10; ++k) v[k] = st[base + k*sM];
#pragma unroll
          for (int r2 = 0; r2 < 10; ++r2) {
            float2 acc = make_float2(0.f, 0.f);
#pragma unroll
            for (int k = 0; k < 10; ++k) {
              float2 u = U[r2*10 + k];
              acc.x = fmaf(u.x, v[k].x, fmaf(-u.y, v[k].y, acc.x));
              acc.y = fmaf(u.x, v[k].y, fmaf( u.y, v[k].x, acc.y));
            }
            if (kerr) {
              float sn, cs; sincosf(angb + k3*(float)(r2*r2), &sn, &cs);
              acc = make_float2(acc.x*cs - acc.y*sn, acc.x*sn + acc.y*cs);
            }
            st[base + r2*sM] = acc;
          }
        }
        __syncthreads();
      }
    }
  }

  // ---- photon-number expectations (wave shuffle reduce) ----
  float a0 = 0.f, a1 = 0.f, a2 = 0.f, a3 = 0.f;
  for (int e = t; e < 10000; e += 1024) {
    int ph = e + e/10 + e/100;
    float2 z = st[ph];
    float pz = z.x*z.x + z.y*z.y;
    a0 += pz * (float)(e/1000);
    a1 += pz * (float)((e/100)%10);
    a2 += pz * (float)((e/10)%10);
    a3 += pz * (float)(e%10);
  }
  for (int off2 = 32; off2 > 0; off2 >>= 1) {
    a0 += __shfl_down(a0, off2, 64);
    a1 += __shfl_down(a1, off2, 64);
    a2 += __shfl_down(a2, off2, 64);
    a3 += __shfl_down(a3, off2, 64);
  }
  if (lane == 0) {
    redw[wv*4+0] = a0; redw[wv*4+1] = a1;
    redw[wv*4+2] = a2; redw[wv*4+3] = a3;
  }
  __syncthreads();
  if (t < 4) {
    float s = 0.f;
    for (int ww = 0; ww < 16; ++ww) s += redw[ww*4 + t];
    out[b*4 + t] = s;
  }
}

extern "C" void kernel_launch(void* const* d_in, const int* in_sizes, int n_in,
                              void* d_out, int out_size, void* d_ws, size_t ws_size,
                              hipStream_t stream) {
  const void* inp = d_in[0];
  const void* w   = d_in[1];
  float* out = (float*)d_out;           // reference output dtype is float32
  int*    flag  = (int*)d_ws;           // 16-byte header
  float2* slots = (float2*)((char*)d_ws + 16);

  sniff_dtype<<<dim3(1), dim3(256), 0, stream>>>(inp, in_sizes[0], flag);
  build_gens<<<dim3(NSLOTS), dim3(128), 0, stream>>>(slots, inp, w, flag);
  expm_all<<<dim3(NSLOTS), dim3(128), 0, stream>>>(slots);
  fused_circuit<<<dim3(NB), dim3(1024), 0, stream>>>(slots, w, flag, out);
}

// Round 8
// 463.111 us; speedup vs baseline: 2.0189x; 1.5885x over previous
//
#include <hip/hip_runtime.h>
#include <hip/hip_bf16.h>

#define CUT 10
#define NB 256
#define NLAYERS 4
#define WSTRIDE 48

// slot map (each slot = padded 10x10 complex, 100 float2)
#define SLOT_S0 0
#define SLOT_DM 1      // 1024 displacement-prep matrices
#define SLOT_SQ 1025   // 16 squeezers (l*4+m)
#define SLOT_DS 1041   // 16 displacements (l*4+m)
#define SLOT_BS 1057   // 48 gates * 19 photon-number blocks
#define NSLOTS  1969

typedef __hip_bfloat16 bf16;

// physical (bank-swizzled) per-mode strides: ph = 1110*n0 + 111*n1 + 11*n2 + n3
#define F0 1110
#define F1 111
#define F2 11
#define F3 1
#define ST_PHYS 11100

// read element i of a buffer whose dtype (f32 vs bf16) was sniffed at runtime
__device__ __forceinline__ float readv(const void* p, int i, int isf32) {
  if (isf32) return ((const float*)p)[i];
  return __bfloat162float(((const bf16*)p)[i]);
}

// chunk permutation: wave w handles chunks g_perm[w][0..2]; chunk c: N=c/2,
// spec offset (c&1)*64. Balanced so per-wave sum(d^2) is ~84 (range 76..100).
__device__ const signed char g_perm[16][3] = {
  {18,-1,-1},{19,-1,-1},{16, 0,-1},{17, 1,-1},{20,36,-1},{21,37,-1},
  {14, 6,34},{15, 7,35},{22,30,-1},{23,31,-1},{12, 8, 4},{13, 9, 5},
  {24,28,32},{25,29,33},{10,26, 2},{11,27, 3}
};

// BS pair tables (physical strides), pair order (0,1),(0,2),(0,3),(1,2),(1,3),(2,3)
__device__ const int c_sI[6]   = {F0,F0,F0,F1,F1,F2};
__device__ const int c_sJ[6]   = {F1,F2,F3,F2,F3,F3};
__device__ const int c_sA[6]   = {F2,F1,F1,F0,F0,F0};   // slow spectator (hi digit)
__device__ const int c_sB[6]   = {F3,F3,F2,F3,F2,F1};   // fast spectator (lo digit)
// single-mode gate tables: gate mode m, spectators ascending
__device__ const int c_sM[4]   = {F0,F1,F2,F3};
__device__ const int c_pA[4]   = {F1,F0,F0,F0};
__device__ const int c_pB[4]   = {F2,F2,F1,F1};
__device__ const int c_pC[4]   = {F3,F3,F3,F2};

// ------------------- K0: sniff input dtype -------------------
__global__ void sniff_dtype(const void* p, int n_elems, int* flag) {
  __shared__ float red[256];
  const unsigned short* h = (const unsigned short*)p;
  int t = threadIdx.x;
  float mx = 0.f;
  for (int i = t; i < n_elems; i += 256) {
    unsigned short u = h[i];
    bf16 bv = *(const bf16*)&u;
    float v = fabsf(__bfloat162float(bv));
    if (!(v < 1e30f)) v = 1e30f;
    mx = fmaxf(mx, v);
  }
  red[t] = mx;
  __syncthreads();
  for (int off = 128; off > 0; off >>= 1) {
    if (t < off) red[t] = fmaxf(red[t], red[t + off]);
    __syncthreads();
  }
  if (t == 0) *flag = (red[0] > 1000.f) ? 1 : 0;  // 1 => buffer is really f32
}

// ------------------- K1: build all generators -------------------
__global__ void build_gens(float2* slots, const void* inp, const void* w,
                           const int* flag) {
  int s = blockIdx.x;
  int t = threadIdx.x;
  if (t >= 100) return;
  int isf32 = *flag;
  int i = t / 10, j = t % 10;
  float2 val = make_float2(0.f, 0.f);
  if (s == SLOT_S0) {
    if (j == i + 2)      { float c = sqrtf((float)((i+1)*(i+2))); val.y = -0.25f*c; }
    else if (i == j + 2) { float c = sqrtf((float)((j+1)*(j+2))); val.y = -0.25f*c; }
  } else if (s < SLOT_SQ) {
    int k = s - SLOT_DM;
    float r = readv(inp, k, isf32);
    if (i == j + 1)      val.x =  r * sqrtf((float)(j+1));
    else if (j == i + 1) val.x = -r * sqrtf((float)(i+1));
  } else if (s < SLOT_DS) {
    int k = s - SLOT_SQ; int l = k >> 2; int m = k & 3;
    float r = readv(w, l*WSTRIDE + 16 + m, isf32);
    if (j == i + 2)      val.x =  0.5f*r*sqrtf((float)((i+1)*(i+2)));
    else if (i == j + 2) val.x = -0.5f*r*sqrtf((float)((j+1)*(j+2)));
  } else if (s < SLOT_BS) {
    int k = s - SLOT_DS; int l = k >> 2; int m = k & 3;
    float rd = readv(w, l*WSTRIDE + 36 + m, isf32);
    float ph = readv(w, l*WSTRIDE + 40 + m, isf32);
    float ar = rd * cosf(ph), ai = rd * sinf(ph);
    if (i == j + 1)      { float c = sqrtf((float)(j+1)); val.x =  ar*c; val.y = ai*c; }
    else if (j == i + 1) { float c = sqrtf((float)(i+1)); val.x = -ar*c; val.y = ai*c; }
  } else {
    int rel = s - SLOT_BS;
    int g = rel / 19; int N = rel % 19;
    int l = g / 12; int h = (g % 12) / 6; int p = g % 6;
    float th = readv(w, l*WSTRIDE + (h ? 20 : 0) + p, isf32);
    float ph = readv(w, l*WSTRIDE + (h ? 26 : 6) + p, isf32);
    int lo = max(0, N - 9), hi = min(9, N);
    int d = hi - lo + 1;
    if (i < d && j < d) {
      if (i == j + 1) {
        float c = sqrtf((float)((lo + j + 1) * (N - lo - j)));
        val.x = th * cosf(ph) * c; val.y = th * sinf(ph) * c;
      } else if (j == i + 1) {
        float c = sqrtf((float)((lo + i + 1) * (N - lo - i)));
        val.x = -th * cosf(ph) * c; val.y = th * sinf(ph) * c;
      }
    }
  }
  slots[(size_t)s * 100 + t] = val;
}

// ------------------- K2: generic expm (scaling-squaring + Taylor) -------------------
__global__ void expm_all(float2* slots) {
  __shared__ float2 T[100], P[100], R[100];
  __shared__ float rowsum[10];
  __shared__ int sshift;
  int s = blockIdx.x, t = threadIdx.x;
  int i = t / 10, j = t % 10;
  float2* G = slots + (size_t)s * 100;
  if (t < 100) T[t] = G[t];
  __syncthreads();
  if (t < 10) {
    float sum = 0.f;
    for (int c = 0; c < 10; ++c) { float2 z = T[t*10+c]; sum += fabsf(z.x) + fabsf(z.y); }
    rowsum[t] = sum;
  }
  __syncthreads();
  if (t == 0) {
    float nm = 0.f;
    for (int r = 0; r < 10; ++r) nm = fmaxf(nm, rowsum[r]);
    int sc = 0;
    if (!(nm < 1e6f)) sc = 0;
    else if (nm > 0.25f) sc = (int)ceilf(log2f(nm * 4.f));
    sshift = min(max(sc, 0), 40);
  }
  __syncthreads();
  int sh = sshift;
  float scl = ldexpf(1.f, -sh);
  if (t < 100) {
    float2 z = T[t]; z.x *= scl; z.y *= scl;
    T[t] = z; P[t] = z;
    R[t] = make_float2(z.x + (i == j ? 1.f : 0.f), z.y);
  }
  __syncthreads();
  for (int k = 2; k <= 12; ++k) {
    float2 acc = make_float2(0.f, 0.f);
    if (t < 100) {
      for (int c = 0; c < 10; ++c) {
        float2 a = P[i*10+c], b = T[c*10+j];
        acc.x += a.x*b.x - a.y*b.y;
        acc.y += a.x*b.y + a.y*b.x;
      }
      float inv = 1.f / (float)k;
      acc.x *= inv; acc.y *= inv;
    }
    __syncthreads();
    if (t < 100) { P[t] = acc; R[t].x += acc.x; R[t].y += acc.y; }
    __syncthreads();
  }
  for (int q = 0; q < sh; ++q) {
    float2 acc = make_float2(0.f, 0.f);
    if (t < 100) {
      for (int c = 0; c < 10; ++c) {
        float2 a = R[i*10+c], b = R[c*10+j];
        acc.x += a.x*b.x - a.y*b.y;
        acc.y += a.x*b.y + a.y*b.x;
      }
    }
    __syncthreads();
    if (t < 100) R[t] = acc;
    __syncthreads();
  }
  if (t < 100) G[t] = R[t];
}

// ------------------- K3: fused circuit — one block per batch, state in LDS -------------------
// LDS budget: state 88.8K + smU 25.6K + bsU(double-buffered) 30.4K + misc ~0.6K
// = 145.4K < 160K -> still 1 block/CU; waves_per_eu(4,4) keeps VGPR cap at 128.
__global__ __launch_bounds__(1024) __attribute__((amdgpu_waves_per_eu(4, 4)))
void fused_circuit(
    const float2* __restrict__ slots, const void* __restrict__ w,
    const int* __restrict__ flag, float* __restrict__ out)
{
  __shared__ float2 st[ST_PHYS];    // ~89 KB swizzled state
  __shared__ float2 smU[3200];      // all 32 single-mode U's (SQ then DS, contiguous)
  __shared__ float2 bsU[3800];      // double-buffered BS gate (19 blocks x 100)
  __shared__ float2 psi[4][10];
  __shared__ float redw[64];
  const int b = blockIdx.x, t = threadIdx.x;
  const int wv = t >> 6, lane = t & 63;
  const int isf32 = *flag;

  const bool smv = (t < 1000);
  const int q0 = t / 100, q1 = (t / 10) % 10, q2 = t % 10;

  // ---- initial product state ----
  if (t < 40) {
    int m = t / 10, r = t % 10;
    const float2* Dm = slots + (size_t)(SLOT_DM + b*4 + m) * 100;
    float2 acc = make_float2(0.f, 0.f);
    for (int c = 0; c < 10; ++c) {
      float2 a = Dm[r*10 + c];
      float2 vv = slots[(size_t)c * 10];   // S0 column 0
      acc.x += a.x*vv.x - a.y*vv.y;
      acc.y += a.x*vv.y + a.y*vv.x;
    }
    psi[m][r] = acc;
  }
  // stage all single-mode U's (contiguous 3200 float2 starting at SLOT_SQ)
  for (int i = t; i < 3200; i += 1024)
    smU[i] = slots[(size_t)SLOT_SQ * 100 + i];
  // stage BS gate 0 into buffer 0
  for (int i = t; i < 1900; i += 1024)
    bsU[i] = slots[(size_t)(SLOT_BS + 0) * 100 + i];
  __syncthreads();
  for (int e = t; e < 10000; e += 1024) {
    int ph = e + e/10 + e/100;
    float2 z  = psi[0][e/1000];
    float2 w1 = psi[1][(e/100)%10];
    float2 r1 = make_float2(z.x*w1.x - z.y*w1.y, z.x*w1.y + z.y*w1.x);
    float2 w2 = psi[2][(e/10)%10];
    float2 r2 = make_float2(r1.x*w2.x - r1.y*w2.y, r1.x*w2.y + r1.y*w2.x);
    float2 w3 = psi[3][e%10];
    st[ph] = make_float2(r2.x*w3.x - r2.y*w3.y, r2.x*w3.y + r2.y*w3.x);
  }
  __syncthreads();

  // ---- circuit ----
#pragma unroll 1
  for (int l = 0; l < NLAYERS; ++l) {
#pragma unroll 1
    for (int half = 0; half < 2; ++half) {
      // 6 beamsplitters (vph diag fused into p==5 output)
#pragma unroll 1
      for (int p = 0; p < 6; ++p) {
        const int gidx = l*12 + half*6 + p;
        // prefetch next BS gate's U into the other buffer (that buffer was
        // last READ in pass gidx-1, which a barrier already separates)
        if (gidx + 1 < 48) {
          const float2* src = slots + (size_t)(SLOT_BS + (gidx+1)*19) * 100;
          float2* dst = bsU + ((gidx+1) & 1) * 1900;
          for (int i = t; i < 1900; i += 1024) dst[i] = src[i];
        }
        const float2* Ub = bsU + (gidx & 1) * 1900;
        const int sI = c_sI[p], sJ = c_sJ[p], sA = c_sA[p], sB = c_sB[p];
        const int step = sI - sJ;
        const int fuse = (p == 5);   // pair (2,3): spectators mode0(hi), mode1(lo)
        float f0=0.f, f1=0.f, fdc=0.f, f3=0.f;
        if (fuse) {
          int off = l*WSTRIDE + (half ? 32 : 12);
          f0 = readv(w, off+0, isf32); f1 = readv(w, off+1, isf32);
          float f2 = readv(w, off+2, isf32); f3 = readv(w, off+3, isf32);
          fdc = f2 - f3;
        }
#pragma unroll
        for (int r = 0; r < 3; ++r) {
          int c = g_perm[wv][r];
          if (c >= 0) {
            int N = c >> 1;
            int spec = ((c & 1) << 6) + lane;
            if (spec < 100) {
              int lo = max(0, N - 9);
              // d is wave-uniform (chunk = single N) -> scalar loop bound:
              // unrolled iterations beyond sd are s_cbranch-skipped, not masked
              const int sd = __builtin_amdgcn_readfirstlane(min(9, N) - lo + 1);
              int hi10 = spec / 10, lo10 = spec % 10;
              const float2* U = Ub + N*100;
              const int idx0 = hi10*sA + lo10*sB + lo*sI + (N - lo)*sJ;
              float angb = 0.f;
              if (fuse)
                angb = f0*(float)hi10 + f1*(float)lo10
                     + f3*(float)N + fdc*(float)lo;
              float2 v[10];
#pragma unroll
              for (int k = 0; k < 10; ++k) if (k < sd) v[k] = st[idx0 + k*step];
#pragma unroll
              for (int rr = 0; rr < 10; ++rr) if (rr < sd) {
                float2 acc = make_float2(0.f, 0.f);
#pragma unroll
                for (int k = 0; k < 10; ++k) if (k < sd) {
                  float2 u = U[rr*10 + k];
                  acc.x = fmaf(u.x, v[k].x, fmaf(-u.y, v[k].y, acc.x));
                  acc.y = fmaf(u.x, v[k].y, fmaf( u.y, v[k].x, acc.y));
                }
                if (fuse) {
                  float sn, cs; sincosf(angb + fdc*(float)rr, &sn, &cs);
                  acc = make_float2(acc.x*cs - acc.y*sn, acc.x*sn + acc.y*cs);
                }
                st[idx0 + rr*step] = acc;   // v[] is in regs; line is lane-private
              }
            }
          }
        }
        __syncthreads();
      }
      // 4 single-mode gates (squeeze half 0 / displace half 1, Kerr fused on last)
#pragma unroll 1
      for (int m = 0; m < 4; ++m) {
        const int uslot = (half == 0) ? (l*4 + m) : (16 + l*4 + m);
        const float2* U = smU + uslot * 100;
        const int sM = c_sM[m], pA = c_pA[m], pB = c_pB[m], pC = c_pC[m];
        const int kerr = (half == 1 && m == 3);  // q0,q1,q2 = n0,n1,n2
        float k0=0.f, k1=0.f, k2=0.f, k3=0.f;
        if (kerr) {
          int off = l*WSTRIDE + 44;
          k0 = readv(w, off+0, isf32); k1 = readv(w, off+1, isf32);
          k2 = readv(w, off+2, isf32); k3 = readv(w, off+3, isf32);
        }
        if (smv) {
          int base = q0*pA + q1*pB + q2*pC;
          float angb = 0.f;
          if (kerr) angb = k0*(float)(q0*q0) + k1*(float)(q1*q1) + k2*(float)(q2*q2);
          float2 v[10];
#pragma unroll
          for (int k = 0; k < 10; ++k) v[k] = st[base + k*sM];
#pragma unroll
          for (int r2 = 0; r2 < 10; ++r2) {
            float2 acc = make_float2(0.f, 0.f);
#pragma unroll
            for (int k = 0; k < 10; ++k) {
              float2 u = U[r2*10 + k];
              acc.x = fmaf(u.x, v[k].x, fmaf(-u.y, v[k].y, acc.x));
              acc.y = fmaf(u.x, v[k].y, fmaf( u.y, v[k].x, acc.y));
            }
            if (kerr) {
              float sn, cs; sincosf(angb + k3*(float)(r2*r2), &sn, &cs);
              acc = make_float2(acc.x*cs - acc.y*sn, acc.x*sn + acc.y*cs);
            }
            st[base + r2*sM] = acc;
          }
        }
        __syncthreads();
      }
    }
  }

  // ---- photon-number expectations (wave shuffle reduce) ----
  float a0 = 0.f, a1 = 0.f, a2 = 0.f, a3 = 0.f;
  for (int e = t; e < 10000; e += 1024) {
    int ph = e + e/10 + e/100;
    float2 z = st[ph];
    float pz = z.x*z.x + z.y*z.y;
    a0 += pz * (float)(e/1000);
    a1 += pz * (float)((e/100)%10);
    a2 += pz * (float)((e/10)%10);
    a3 += pz * (float)(e%10);
  }
  for (int off2 = 32; off2 > 0; off2 >>= 1) {
    a0 += __shfl_down(a0, off2, 64);
    a1 += __shfl_down(a1, off2, 64);
    a2 += __shfl_down(a2, off2, 64);
    a3 += __shfl_down(a3, off2, 64);
  }
  if (lane == 0) {
    redw[wv*4+0] = a0; redw[wv*4+1] = a1;
    redw[wv*4+2] = a2; redw[wv*4+3] = a3;
  }
  __syncthreads();
  if (t < 4) {
    float s = 0.f;
    for (int ww = 0; ww < 16; ++ww) s += redw[ww*4 + t];
    out[b*4 + t] = s;
  }
}

extern "C" void kernel_launch(void* const* d_in, const int* in_sizes, int n_in,
                              void* d_out, int out_size, void* d_ws, size_t ws_size,
                              hipStream_t stream) {
  const void* inp = d_in[0];
  const void* w   = d_in[1];
  float* out = (float*)d_out;           // reference output dtype is float32
  int*    flag  = (int*)d_ws;           // 16-byte header
  float2* slots = (float2*)((char*)d_ws + 16);

  sniff_dtype<<<dim3(1), dim3(256), 0, stream>>>(inp, in_sizes[0], flag);
  build_gens<<<dim3(NSLOTS), dim3(128), 0, stream>>>(slots, inp, w, flag);
  expm_all<<<dim3(NSLOTS), dim3(128), 0, stream>>>(slots);
  fused_circuit<<<dim3(NB), dim3(1024), 0, stream>>>(slots, w, flag, out);
}

// Round 9
// 435.892 us; speedup vs baseline: 2.1450x; 1.0624x over previous
//
#include <hip/hip_runtime.h>
#include <hip/hip_bf16.h>

#define CUT 10
#define NB 256
#define NLAYERS 4
#define WSTRIDE 48

// slot map (each slot = padded 10x10 complex, 100 float2)
#define SLOT_S0 0
#define SLOT_DM 1      // 1024 displacement-prep matrices
#define SLOT_SQ 1025   // 16 squeezers (l*4+m)
#define SLOT_DS 1041   // 16 displacements (l*4+m)
#define SLOT_BS 1057   // 48 gates * 19 photon-number blocks
#define NSLOTS  1969

typedef __hip_bfloat16 bf16;

// physical (bank-swizzled) per-mode strides: ph = 1110*n0 + 111*n1 + 11*n2 + n3
#define F0 1110
#define F1 111
#define F2 11
#define F3 1
#define ST_PHYS 11100

// read element i of a buffer whose dtype (f32 vs bf16) was sniffed at runtime
__device__ __forceinline__ float readv(const void* p, int i, int isf32) {
  if (isf32) return ((const float*)p)[i];
  return __bfloat162float(((const bf16*)p)[i]);
}

// packed complex MAC: acc += u * v using 2x v_pk_fma_f32 (vs 4x v_fma_f32)
//   inst1: acc.lo += u.lo*v.lo ; acc.hi += u.lo*v.hi
//   inst2: acc.lo += -u.hi*v.hi; acc.hi += u.hi*v.lo
__device__ __forceinline__ void cmac(float2& a, float2 u, float2 v) {
  asm("v_pk_fma_f32 %0, %1, %2, %0 op_sel:[0,0,0] op_sel_hi:[0,1,1]\n\t"
      "v_pk_fma_f32 %0, %1, %2, %0 op_sel:[1,1,0] op_sel_hi:[1,0,1] neg_lo:[1,0,0]"
      : "+v"(a) : "v"(u), "v"(v));
}

// chunk permutation: wave w handles chunks g_perm[w][0..2]; chunk c: N=c/2,
// spec offset (c&1)*64. Balanced so per-wave sum(d^2) is ~84 (range 76..100).
__device__ const signed char g_perm[16][3] = {
  {18,-1,-1},{19,-1,-1},{16, 0,-1},{17, 1,-1},{20,36,-1},{21,37,-1},
  {14, 6,34},{15, 7,35},{22,30,-1},{23,31,-1},{12, 8, 4},{13, 9, 5},
  {24,28,32},{25,29,33},{10,26, 2},{11,27, 3}
};

// ------------------- K0: sniff input dtype -------------------
__global__ void sniff_dtype(const void* p, int n_elems, int* flag) {
  __shared__ float red[256];
  const unsigned short* h = (const unsigned short*)p;
  int t = threadIdx.x;
  float mx = 0.f;
  for (int i = t; i < n_elems; i += 256) {
    unsigned short u = h[i];
    bf16 bv = *(const bf16*)&u;
    float v = fabsf(__bfloat162float(bv));
    if (!(v < 1e30f)) v = 1e30f;
    mx = fmaxf(mx, v);
  }
  red[t] = mx;
  __syncthreads();
  for (int off = 128; off > 0; off >>= 1) {
    if (t < off) red[t] = fmaxf(red[t], red[t + off]);
    __syncthreads();
  }
  if (t == 0) *flag = (red[0] > 1000.f) ? 1 : 0;  // 1 => buffer is really f32
}

// ------------------- K1: build all generators -------------------
__global__ void build_gens(float2* slots, const void* inp, const void* w,
                           const int* flag) {
  int s = blockIdx.x;
  int t = threadIdx.x;
  if (t >= 100) return;
  int isf32 = *flag;
  int i = t / 10, j = t % 10;
  float2 val = make_float2(0.f, 0.f);
  if (s == SLOT_S0) {
    if (j == i + 2)      { float c = sqrtf((float)((i+1)*(i+2))); val.y = -0.25f*c; }
    else if (i == j + 2) { float c = sqrtf((float)((j+1)*(j+2))); val.y = -0.25f*c; }
  } else if (s < SLOT_SQ) {
    int k = s - SLOT_DM;
    float r = readv(inp, k, isf32);
    if (i == j + 1)      val.x =  r * sqrtf((float)(j+1));
    else if (j == i + 1) val.x = -r * sqrtf((float)(i+1));
  } else if (s < SLOT_DS) {
    int k = s - SLOT_SQ; int l = k >> 2; int m = k & 3;
    float r = readv(w, l*WSTRIDE + 16 + m, isf32);
    if (j == i + 2)      val.x =  0.5f*r*sqrtf((float)((i+1)*(i+2)));
    else if (i == j + 2) val.x = -0.5f*r*sqrtf((float)((j+1)*(j+2)));
  } else if (s < SLOT_BS) {
    int k = s - SLOT_DS; int l = k >> 2; int m = k & 3;
    float rd = readv(w, l*WSTRIDE + 36 + m, isf32);
    float ph = readv(w, l*WSTRIDE + 40 + m, isf32);
    float ar = rd * cosf(ph), ai = rd * sinf(ph);
    if (i == j + 1)      { float c = sqrtf((float)(j+1)); val.x =  ar*c; val.y = ai*c; }
    else if (j == i + 1) { float c = sqrtf((float)(i+1)); val.x = -ar*c; val.y = ai*c; }
  } else {
    int rel = s - SLOT_BS;
    int g = rel / 19; int N = rel % 19;
    int l = g / 12; int h = (g % 12) / 6; int p = g % 6;
    float th = readv(w, l*WSTRIDE + (h ? 20 : 0) + p, isf32);
    float ph = readv(w, l*WSTRIDE + (h ? 26 : 6) + p, isf32);
    int lo = max(0, N - 9), hi = min(9, N);
    int d = hi - lo + 1;
    if (i < d && j < d) {
      if (i == j + 1) {
        float c = sqrtf((float)((lo + j + 1) * (N - lo - j)));
        val.x = th * cosf(ph) * c; val.y = th * sinf(ph) * c;
      } else if (j == i + 1) {
        float c = sqrtf((float)((lo + i + 1) * (N - lo - i)));
        val.x = -th * cosf(ph) * c; val.y = th * sinf(ph) * c;
      }
    }
  }
  slots[(size_t)s * 100 + t] = val;
}

// ------------------- K2: generic expm (scaling-squaring + Taylor) -------------------
__global__ void expm_all(float2* slots) {
  __shared__ float2 T[100], P[100], R[100];
  __shared__ float rowsum[10];
  __shared__ int sshift;
  int s = blockIdx.x, t = threadIdx.x;
  int i = t / 10, j = t % 10;
  float2* G = slots + (size_t)s * 100;
  if (t < 100) T[t] = G[t];
  __syncthreads();
  if (t < 10) {
    float sum = 0.f;
    for (int c = 0; c < 10; ++c) { float2 z = T[t*10+c]; sum += fabsf(z.x) + fabsf(z.y); }
    rowsum[t] = sum;
  }
  __syncthreads();
  if (t == 0) {
    float nm = 0.f;
    for (int r = 0; r < 10; ++r) nm = fmaxf(nm, rowsum[r]);
    int sc = 0;
    if (!(nm < 1e6f)) sc = 0;
    else if (nm > 0.25f) sc = (int)ceilf(log2f(nm * 4.f));
    sshift = min(max(sc, 0), 40);
  }
  __syncthreads();
  int sh = sshift;
  float scl = ldexpf(1.f, -sh);
  if (t < 100) {
    float2 z = T[t]; z.x *= scl; z.y *= scl;
    T[t] = z; P[t] = z;
    R[t] = make_float2(z.x + (i == j ? 1.f : 0.f), z.y);
  }
  __syncthreads();
  for (int k = 2; k <= 12; ++k) {
    float2 acc = make_float2(0.f, 0.f);
    if (t < 100) {
      for (int c = 0; c < 10; ++c) {
        float2 a = P[i*10+c], b = T[c*10+j];
        acc.x += a.x*b.x - a.y*b.y;
        acc.y += a.x*b.y + a.y*b.x;
      }
      float inv = 1.f / (float)k;
      acc.x *= inv; acc.y *= inv;
    }
    __syncthreads();
    if (t < 100) { P[t] = acc; R[t].x += acc.x; R[t].y += acc.y; }
    __syncthreads();
  }
  for (int q = 0; q < sh; ++q) {
    float2 acc = make_float2(0.f, 0.f);
    if (t < 100) {
      for (int c = 0; c < 10; ++c) {
        float2 a = R[i*10+c], b = R[c*10+j];
        acc.x += a.x*b.x - a.y*b.y;
        acc.y += a.x*b.y + a.y*b.x;
      }
    }
    __syncthreads();
    if (t < 100) R[t] = acc;
    __syncthreads();
  }
  if (t < 100) G[t] = R[t];
}

// ---- BS gate body: compile-time strides -> immediate-offset LDS addressing ----
template<int sI, int sJ, int sA, int sB, bool FUSE>
__device__ __forceinline__ void bs_gate(
    float2* st, const float2* __restrict__ Ub, int lane,
    int ch0, int ch1, int ch2,
    float f0, float f1, float fdc, float f3)
{
  constexpr int step = sI - sJ;
#pragma unroll
  for (int r = 0; r < 3; ++r) {
    const int c = (r == 0) ? ch0 : (r == 1) ? ch1 : ch2;
    if (c >= 0) {
      int N = c >> 1;
      int spec = ((c & 1) << 6) + lane;
      if (spec < 100) {
        int lo = max(0, N - 9);
        // d is wave-uniform (chunk = single N) -> scalar loop bound
        const int sd = __builtin_amdgcn_readfirstlane(min(9, N) - lo + 1);
        int hi10 = spec / 10, lo10 = spec % 10;
        const float2* U = Ub + N*100;
        float2* base = st + hi10*sA + lo10*sB + lo*sI + (N - lo)*sJ;
        float angb = 0.f;
        if (FUSE)
          angb = f0*(float)hi10 + f1*(float)lo10 + f3*(float)N + fdc*(float)lo;
        float2 v[10];
#pragma unroll
        for (int k = 0; k < 10; ++k) if (k < sd) v[k] = base[k*step];
#pragma unroll
        for (int rr = 0; rr < 10; ++rr) if (rr < sd) {
          float2 acc = make_float2(0.f, 0.f);
          const float4* Urow = (const float4*)(U + rr*10);  // 16B-aligned rows
#pragma unroll
          for (int kp = 0; kp < 5; ++kp) if (2*kp < sd) {
            float4 uu = Urow[kp];       // reads elem 2kp+1 too — always in-bounds (padded)
            cmac(acc, make_float2(uu.x, uu.y), v[2*kp]);
            if (2*kp + 1 < sd) cmac(acc, make_float2(uu.z, uu.w), v[2*kp+1]);
          }
          if (FUSE) {
            float sn, cs; sincosf(angb + fdc*(float)rr, &sn, &cs);
            acc = make_float2(acc.x*cs - acc.y*sn, acc.x*sn + acc.y*cs);
          }
          base[rr*step] = acc;   // v[] is in regs; line is lane-private
        }
      }
    }
  }
}

// ---- single-mode gate body: compile-time strides ----
template<int sM, int pA, int pB, int pC, bool KERR>
__device__ __forceinline__ void sm_gate(
    float2* st, const float2* __restrict__ U,
    bool smv, int q0, int q1, int q2,
    float k0, float k1, float k2, float k3)
{
  if (!smv) return;
  float2* base = st + q0*pA + q1*pB + q2*pC;
  float angb = 0.f;
  if (KERR) angb = k0*(float)(q0*q0) + k1*(float)(q1*q1) + k2*(float)(q2*q2);
  float2 v[10];
#pragma unroll
  for (int k = 0; k < 10; ++k) v[k] = base[k*sM];
#pragma unroll
  for (int rr = 0; rr < 10; ++rr) {
    float2 acc = make_float2(0.f, 0.f);
    const float4* Urow = (const float4*)(U + rr*10);
#pragma unroll
    for (int kp = 0; kp < 5; ++kp) {
      float4 uu = Urow[kp];
      cmac(acc, make_float2(uu.x, uu.y), v[2*kp]);
      cmac(acc, make_float2(uu.z, uu.w), v[2*kp+1]);
    }
    if (KERR) {
      float sn, cs; sincosf(angb + k3*(float)(rr*rr), &sn, &cs);
      acc = make_float2(acc.x*cs - acc.y*sn, acc.x*sn + acc.y*cs);
    }
    base[rr*sM] = acc;
  }
}

// ------------------- K3: fused circuit — one block per batch, state in LDS -------------------
// LDS: state 88.8K + smU 25.6K + bsU(dbuf) 30.4K + misc ~0.6K = 145.4K < 160K
__global__ __launch_bounds__(1024) __attribute__((amdgpu_waves_per_eu(4, 4)))
void fused_circuit(
    const float2* __restrict__ slots, const void* __restrict__ w,
    const int* __restrict__ flag, float* __restrict__ out)
{
  __shared__ float2 st[ST_PHYS];                  // ~89 KB swizzled state
  __shared__ __align__(16) float2 smU[3200];      // all 32 single-mode U's
  __shared__ __align__(16) float2 bsU[3800];      // double-buffered BS gate
  __shared__ float2 psi[4][10];
  __shared__ float redw[64];
  const int b = blockIdx.x, t = threadIdx.x;
  const int wv = t >> 6, lane = t & 63;
  const int isf32 = *flag;

  // per-thread chunk metadata: 3 scalars, compile-time indexed everywhere
  const int ch0 = g_perm[wv][0], ch1 = g_perm[wv][1], ch2 = g_perm[wv][2];
  const bool smv = (t < 1000);
  const int q0 = t / 100, q1 = (t / 10) % 10, q2 = t % 10;

  // ---- initial product state ----
  if (t < 40) {
    int m = t / 10, r = t % 10;
    const float2* Dm = slots + (size_t)(SLOT_DM + b*4 + m) * 100;
    float2 acc = make_float2(0.f, 0.f);
    for (int c = 0; c < 10; ++c) {
      float2 a = Dm[r*10 + c];
      float2 vv = slots[(size_t)c * 10];   // S0 column 0
      acc.x += a.x*vv.x - a.y*vv.y;
      acc.y += a.x*vv.y + a.y*vv.x;
    }
    psi[m][r] = acc;
  }
  for (int i = t; i < 3200; i += 1024)
    smU[i] = slots[(size_t)SLOT_SQ * 100 + i];
  for (int i = t; i < 1900; i += 1024)
    bsU[i] = slots[(size_t)(SLOT_BS + 0) * 100 + i];
  __syncthreads();
  for (int e = t; e < 10000; e += 1024) {
    int ph = e + e/10 + e/100;
    float2 z  = psi[0][e/1000];
    float2 w1 = psi[1][(e/100)%10];
    float2 r1 = make_float2(z.x*w1.x - z.y*w1.y, z.x*w1.y + z.y*w1.x);
    float2 w2 = psi[2][(e/10)%10];
    float2 r2 = make_float2(r1.x*w2.x - r1.y*w2.y, r1.x*w2.y + r1.y*w2.x);
    float2 w3 = psi[3][e%10];
    st[ph] = make_float2(r2.x*w3.x - r2.y*w3.y, r2.x*w3.y + r2.y*w3.x);
  }
  __syncthreads();

  auto prefetch = [&](int next) {
    if (next < 48) {
      const float2* src = slots + (size_t)(SLOT_BS + next*19) * 100;
      float2* dst = bsU + (next & 1) * 1900;
      for (int i = t; i < 1900; i += 1024) dst[i] = src[i];
    }
  };

  // ---- circuit ----
#pragma unroll 1
  for (int l = 0; l < NLAYERS; ++l) {
#pragma unroll 1
    for (int half = 0; half < 2; ++half) {
      const int g6 = l*12 + half*6;
      // fused vph coefficients (applied on p==5)
      int foff = l*WSTRIDE + (half ? 32 : 12);
      float f0 = readv(w, foff+0, isf32), f1 = readv(w, foff+1, isf32);
      float f2v = readv(w, foff+2, isf32), f3 = readv(w, foff+3, isf32);
      float fdc = f2v - f3;

      prefetch(g6+1);
      bs_gate<F0,F1,F2,F3,false>(st, bsU+((g6+0)&1)*1900, lane, ch0,ch1,ch2, 0,0,0,0);
      __syncthreads();
      prefetch(g6+2);
      bs_gate<F0,F2,F1,F3,false>(st, bsU+((g6+1)&1)*1900, lane, ch0,ch1,ch2, 0,0,0,0);
      __syncthreads();
      prefetch(g6+3);
      bs_gate<F0,F3,F1,F2,false>(st, bsU+((g6+2)&1)*1900, lane, ch0,ch1,ch2, 0,0,0,0);
      __syncthreads();
      prefetch(g6+4);
      bs_gate<F1,F2,F0,F3,false>(st, bsU+((g6+3)&1)*1900, lane, ch0,ch1,ch2, 0,0,0,0);
      __syncthreads();
      prefetch(g6+5);
      bs_gate<F1,F3,F0,F2,false>(st, bsU+((g6+4)&1)*1900, lane, ch0,ch1,ch2, 0,0,0,0);
      __syncthreads();
      prefetch(g6+6);
      bs_gate<F2,F3,F0,F1,true >(st, bsU+((g6+5)&1)*1900, lane, ch0,ch1,ch2, f0,f1,fdc,f3);
      __syncthreads();

      // 4 single-mode gates (squeeze half 0 / displace half 1, Kerr fused on last)
      const int ub = (half == 0) ? (l*4) : (16 + l*4);
      float k0=0.f, k1=0.f, k2=0.f, k3=0.f;
      if (half == 1) {
        int koff = l*WSTRIDE + 44;
        k0 = readv(w, koff+0, isf32); k1 = readv(w, koff+1, isf32);
        k2 = readv(w, koff+2, isf32); k3 = readv(w, koff+3, isf32);
      }
      sm_gate<F0,F1,F2,F3,false>(st, smU+(ub+0)*100, smv, q0,q1,q2, 0,0,0,0);
      __syncthreads();
      sm_gate<F1,F0,F2,F3,false>(st, smU+(ub+1)*100, smv, q0,q1,q2, 0,0,0,0);
      __syncthreads();
      sm_gate<F2,F0,F1,F3,false>(st, smU+(ub+2)*100, smv, q0,q1,q2, 0,0,0,0);
      __syncthreads();
      if (half == 1)
        sm_gate<F3,F0,F1,F2,true >(st, smU+(ub+3)*100, smv, q0,q1,q2, k0,k1,k2,k3);
      else
        sm_gate<F3,F0,F1,F2,false>(st, smU+(ub+3)*100, smv, q0,q1,q2, 0,0,0,0);
      __syncthreads();
    }
  }

  // ---- photon-number expectations (wave shuffle reduce) ----
  float a0 = 0.f, a1 = 0.f, a2 = 0.f, a3 = 0.f;
  for (int e = t; e < 10000; e += 1024) {
    int ph = e + e/10 + e/100;
    float2 z = st[ph];
    float pz = z.x*z.x + z.y*z.y;
    a0 += pz * (float)(e/1000);
    a1 += pz * (float)((e/100)%10);
    a2 += pz * (float)((e/10)%10);
    a3 += pz * (float)(e%10);
  }
  for (int off2 = 32; off2 > 0; off2 >>= 1) {
    a0 += __shfl_down(a0, off2, 64);
    a1 += __shfl_down(a1, off2, 64);
    a2 += __shfl_down(a2, off2, 64);
    a3 += __shfl_down(a3, off2, 64);
  }
  if (lane == 0) {
    redw[wv*4+0] = a0; redw[wv*4+1] = a1;
    redw[wv*4+2] = a2; redw[wv*4+3] = a3;
  }
  __syncthreads();
  if (t < 4) {
    float s = 0.f;
    for (int ww = 0; ww < 16; ++ww) s += redw[ww*4 + t];
    out[b*4 + t] = s;
  }
}

extern "C" void kernel_launch(void* const* d_in, const int* in_sizes, int n_in,
                              void* d_out, int out_size, void* d_ws, size_t ws_size,
                              hipStream_t stream) {
  const void* inp = d_in[0];
  const void* w   = d_in[1];
  float* out = (float*)d_out;           // reference output dtype is float32
  int*    flag  = (int*)d_ws;           // 16-byte header
  float2* slots = (float2*)((char*)d_ws + 16);

  sniff_dtype<<<dim3(1), dim3(256), 0, stream>>>(inp, in_sizes[0], flag);
  build_gens<<<dim3(NSLOTS), dim3(128), 0, stream>>>(slots, inp, w, flag);
  expm_all<<<dim3(NSLOTS), dim3(128), 0, stream>>>(slots);
  fused_circuit<<<dim3(NB), dim3(1024), 0, stream>>>(slots, w, flag, out);
}

// Round 10
// 420.235 us; speedup vs baseline: 2.2249x; 1.0373x over previous
//
#include <hip/hip_runtime.h>
#include <hip/hip_bf16.h>

#define CUT 10
#define NB 256
#define NLAYERS 4
#define WSTRIDE 48

// slot map (each slot = padded 10x10 complex, 100 float2)
#define SLOT_S0 0
#define SLOT_DM 1      // 1024 displacement-prep matrices
#define SLOT_SQ 1025   // 16 squeezers (l*4+m)
#define SLOT_DS 1041   // 16 displacements (l*4+m)
#define SLOT_BS 1057   // 48 gates * 19 photon-number blocks
#define NSLOTS  1969

typedef __hip_bfloat16 bf16;

// physical (bank-swizzled) per-mode strides: ph = 1110*n0 + 111*n1 + 11*n2 + n3
#define F0 1110
#define F1 111
#define F2 11
#define F3 1
#define ST_PHYS 11100

// read element i of a buffer whose dtype (f32 vs bf16) was sniffed at runtime
__device__ __forceinline__ float readv(const void* p, int i, int isf32) {
  if (isf32) return ((const float*)p)[i];
  return __bfloat162float(((const bf16*)p)[i]);
}

// packed complex MAC: acc += u * v using 2x v_pk_fma_f32 (vs 4x v_fma_f32)
__device__ __forceinline__ void cmac(float2& a, float2 u, float2 v) {
  asm("v_pk_fma_f32 %0, %1, %2, %0 op_sel:[0,0,0] op_sel_hi:[0,1,1]\n\t"
      "v_pk_fma_f32 %0, %1, %2, %0 op_sel:[1,1,0] op_sel_hi:[1,0,1] neg_lo:[1,0,0]"
      : "+v"(a) : "v"(u), "v"(v));
}

// chunk permutation: wave w handles chunks g_perm[w][0..2]; chunk c: N=c/2,
// spec offset (c&1)*64. Balanced so per-wave sum(d^2) is ~84 (range 76..100).
__device__ const signed char g_perm[16][3] = {
  {18,-1,-1},{19,-1,-1},{16, 0,-1},{17, 1,-1},{20,36,-1},{21,37,-1},
  {14, 6,34},{15, 7,35},{22,30,-1},{23,31,-1},{12, 8, 4},{13, 9, 5},
  {24,28,32},{25,29,33},{10,26, 2},{11,27, 3}
};

// ------------------- K0: sniff input dtype -------------------
__global__ void sniff_dtype(const void* p, int n_elems, int* flag) {
  __shared__ float red[256];
  const unsigned short* h = (const unsigned short*)p;
  int t = threadIdx.x;
  float mx = 0.f;
  for (int i = t; i < n_elems; i += 256) {
    unsigned short u = h[i];
    bf16 bv = *(const bf16*)&u;
    float v = fabsf(__bfloat162float(bv));
    if (!(v < 1e30f)) v = 1e30f;
    mx = fmaxf(mx, v);
  }
  red[t] = mx;
  __syncthreads();
  for (int off = 128; off > 0; off >>= 1) {
    if (t < off) red[t] = fmaxf(red[t], red[t + off]);
    __syncthreads();
  }
  if (t == 0) *flag = (red[0] > 1000.f) ? 1 : 0;  // 1 => buffer is really f32
}

// ------------------- K1: build all generators -------------------
__global__ void build_gens(float2* slots, const void* inp, const void* w,
                           const int* flag) {
  int s = blockIdx.x;
  int t = threadIdx.x;
  if (t >= 100) return;
  int isf32 = *flag;
  int i = t / 10, j = t % 10;
  float2 val = make_float2(0.f, 0.f);
  if (s == SLOT_S0) {
    if (j == i + 2)      { float c = sqrtf((float)((i+1)*(i+2))); val.y = -0.25f*c; }
    else if (i == j + 2) { float c = sqrtf((float)((j+1)*(j+2))); val.y = -0.25f*c; }
  } else if (s < SLOT_SQ) {
    int k = s - SLOT_DM;
    float r = readv(inp, k, isf32);
    if (i == j + 1)      val.x =  r * sqrtf((float)(j+1));
    else if (j == i + 1) val.x = -r * sqrtf((float)(i+1));
  } else if (s < SLOT_DS) {
    int k = s - SLOT_SQ; int l = k >> 2; int m = k & 3;
    float r = readv(w, l*WSTRIDE + 16 + m, isf32);
    if (j == i + 2)      val.x =  0.5f*r*sqrtf((float)((i+1)*(i+2)));
    else if (i == j + 2) val.x = -0.5f*r*sqrtf((float)((j+1)*(j+2)));
  } else if (s < SLOT_BS) {
    int k = s - SLOT_DS; int l = k >> 2; int m = k & 3;
    float rd = readv(w, l*WSTRIDE + 36 + m, isf32);
    float ph = readv(w, l*WSTRIDE + 40 + m, isf32);
    float ar = rd * cosf(ph), ai = rd * sinf(ph);
    if (i == j + 1)      { float c = sqrtf((float)(j+1)); val.x =  ar*c; val.y = ai*c; }
    else if (j == i + 1) { float c = sqrtf((float)(i+1)); val.x = -ar*c; val.y = ai*c; }
  } else {
    int rel = s - SLOT_BS;
    int g = rel / 19; int N = rel % 19;
    int l = g / 12; int h = (g % 12) / 6; int p = g % 6;
    float th = readv(w, l*WSTRIDE + (h ? 20 : 0) + p, isf32);
    float ph = readv(w, l*WSTRIDE + (h ? 26 : 6) + p, isf32);
    int lo = max(0, N - 9), hi = min(9, N);
    int d = hi - lo + 1;
    if (i < d && j < d) {
      if (i == j + 1) {
        float c = sqrtf((float)((lo + j + 1) * (N - lo - j)));
        val.x = th * cosf(ph) * c; val.y = th * sinf(ph) * c;
      } else if (j == i + 1) {
        float c = sqrtf((float)((lo + i + 1) * (N - lo - i)));
        val.x = -th * cosf(ph) * c; val.y = th * sinf(ph) * c;
      }
    }
  }
  slots[(size_t)s * 100 + t] = val;
}

// ------------------- K2: generic expm (scaling-squaring + Taylor) -------------------
__global__ void expm_all(float2* slots) {
  __shared__ float2 T[100], P[100], R[100];
  __shared__ float rowsum[10];
  __shared__ int sshift;
  int s = blockIdx.x, t = threadIdx.x;
  int i = t / 10, j = t % 10;
  float2* G = slots + (size_t)s * 100;
  if (t < 100) T[t] = G[t];
  __syncthreads();
  if (t < 10) {
    float sum = 0.f;
    for (int c = 0; c < 10; ++c) { float2 z = T[t*10+c]; sum += fabsf(z.x) + fabsf(z.y); }
    rowsum[t] = sum;
  }
  __syncthreads();
  if (t == 0) {
    float nm = 0.f;
    for (int r = 0; r < 10; ++r) nm = fmaxf(nm, rowsum[r]);
    int sc = 0;
    if (!(nm < 1e6f)) sc = 0;
    else if (nm > 0.25f) sc = (int)ceilf(log2f(nm * 4.f));
    sshift = min(max(sc, 0), 40);
  }
  __syncthreads();
  int sh = sshift;
  float scl = ldexpf(1.f, -sh);
  if (t < 100) {
    float2 z = T[t]; z.x *= scl; z.y *= scl;
    T[t] = z; P[t] = z;
    R[t] = make_float2(z.x + (i == j ? 1.f : 0.f), z.y);
  }
  __syncthreads();
  for (int k = 2; k <= 12; ++k) {
    float2 acc = make_float2(0.f, 0.f);
    if (t < 100) {
      for (int c = 0; c < 10; ++c) {
        float2 a = P[i*10+c], b = T[c*10+j];
        acc.x += a.x*b.x - a.y*b.y;
        acc.y += a.x*b.y + a.y*b.x;
      }
      float inv = 1.f / (float)k;
      acc.x *= inv; acc.y *= inv;
    }
    __syncthreads();
    if (t < 100) { P[t] = acc; R[t].x += acc.x; R[t].y += acc.y; }
    __syncthreads();
  }
  for (int q = 0; q < sh; ++q) {
    float2 acc = make_float2(0.f, 0.f);
    if (t < 100) {
      for (int c = 0; c < 10; ++c) {
        float2 a = R[i*10+c], b = R[c*10+j];
        acc.x += a.x*b.x - a.y*b.y;
        acc.y += a.x*b.y + a.y*b.x;
      }
    }
    __syncthreads();
    if (t < 100) R[t] = acc;
    __syncthreads();
  }
  if (t < 100) G[t] = R[t];
}

// ---- one BS line: row ping-pong (load row rr+1's U quads while computing rr) ----
template<int sI, int sJ, int sA, int sB, bool FUSE>
__device__ __forceinline__ void bs_chunk(
    float2* st, const float2* __restrict__ U, int sd,
    int hi10, int lo10, int lo, int N, float angb, float fdc)
{
  constexpr int step = sI - sJ;
  float2* base = st + hi10*sA + lo10*sB + lo*sI + (N - lo)*sJ;
  float2 v[10];
#pragma unroll
  for (int k = 0; k < 10; ++k) if (k < sd) v[k] = base[k*step];
  const float4* Uq = (const float4*)U;   // row rr -> quads [rr*5 .. rr*5+4]
  float4 ua[5], ub[5];
#pragma unroll
  for (int q = 0; q < 5; ++q) if (2*q < sd) ua[q] = Uq[q];
#pragma unroll
  for (int rr = 0; rr < 10; rr += 2) {
    if (rr < sd) {
      if (rr + 1 < sd) {
#pragma unroll
        for (int q = 0; q < 5; ++q) if (2*q < sd) ub[q] = Uq[(rr+1)*5 + q];
      }
      float2 acc = make_float2(0.f, 0.f);
#pragma unroll
      for (int q = 0; q < 5; ++q) if (2*q < sd) {
        cmac(acc, make_float2(ua[q].x, ua[q].y), v[2*q]);
        if (2*q + 1 < sd) cmac(acc, make_float2(ua[q].z, ua[q].w), v[2*q+1]);
      }
      if (FUSE) {
        float sn, cs; sincosf(angb + fdc*(float)rr, &sn, &cs);
        acc = make_float2(acc.x*cs - acc.y*sn, acc.x*sn + acc.y*cs);
      }
      base[rr*step] = acc;
    }
    if (rr + 1 < sd) {
      if (rr + 2 < sd) {
#pragma unroll
        for (int q = 0; q < 5; ++q) if (2*q < sd) ua[q] = Uq[(rr+2)*5 + q];
      }
      float2 acc = make_float2(0.f, 0.f);
#pragma unroll
      for (int q = 0; q < 5; ++q) if (2*q < sd) {
        cmac(acc, make_float2(ub[q].x, ub[q].y), v[2*q]);
        if (2*q + 1 < sd) cmac(acc, make_float2(ub[q].z, ub[q].w), v[2*q+1]);
      }
      if (FUSE) {
        float sn, cs; sincosf(angb + fdc*(float)(rr+1), &sn, &cs);
        acc = make_float2(acc.x*cs - acc.y*sn, acc.x*sn + acc.y*cs);
      }
      base[(rr+1)*step] = acc;
    }
  }
}

template<int sI, int sJ, int sA, int sB, bool FUSE>
__device__ __forceinline__ void bs_gate(
    float2* st, const float2* __restrict__ Ub, int lane,
    int ch0, int ch1, int ch2,
    float f0, float f1, float fdc, float f3)
{
#pragma unroll
  for (int r = 0; r < 3; ++r) {
    const int c = (r == 0) ? ch0 : (r == 1) ? ch1 : ch2;
    if (c >= 0) {
      int N = c >> 1;
      int spec = ((c & 1) << 6) + lane;
      if (spec < 100) {
        int lo = max(0, N - 9);
        const int sd = __builtin_amdgcn_readfirstlane(min(9, N) - lo + 1);
        int hi10 = spec / 10, lo10 = spec % 10;
        float angb = 0.f;
        if (FUSE)
          angb = f0*(float)hi10 + f1*(float)lo10 + f3*(float)N + fdc*(float)lo;
        bs_chunk<sI,sJ,sA,sB,FUSE>(st, Ub + N*100, sd, hi10, lo10, lo, N, angb, fdc);
      }
    }
  }
}

// ---- single-mode gate body: row ping-pong, full d=10 ----
template<int sM, int pA, int pB, int pC, bool KERR>
__device__ __forceinline__ void sm_gate(
    float2* st, const float2* __restrict__ U,
    bool smv, int q0, int q1, int q2,
    float k0, float k1, float k2, float k3)
{
  if (!smv) return;
  float2* base = st + q0*pA + q1*pB + q2*pC;
  float angb = 0.f;
  if (KERR) angb = k0*(float)(q0*q0) + k1*(float)(q1*q1) + k2*(float)(q2*q2);
  float2 v[10];
#pragma unroll
  for (int k = 0; k < 10; ++k) v[k] = base[k*sM];
  const float4* Uq = (const float4*)U;
  float4 ua[5], ub[5];
#pragma unroll
  for (int q = 0; q < 5; ++q) ua[q] = Uq[q];
#pragma unroll
  for (int rr = 0; rr < 10; rr += 2) {
    {
      if (rr + 1 < 10) {
#pragma unroll
        for (int q = 0; q < 5; ++q) ub[q] = Uq[(rr+1)*5 + q];
      }
      float2 acc = make_float2(0.f, 0.f);
#pragma unroll
      for (int q = 0; q < 5; ++q) {
        cmac(acc, make_float2(ua[q].x, ua[q].y), v[2*q]);
        cmac(acc, make_float2(ua[q].z, ua[q].w), v[2*q+1]);
      }
      if (KERR) {
        float sn, cs; sincosf(angb + k3*(float)(rr*rr), &sn, &cs);
        acc = make_float2(acc.x*cs - acc.y*sn, acc.x*sn + acc.y*cs);
      }
      base[rr*sM] = acc;
    }
    {
      if (rr + 2 < 10) {
#pragma unroll
        for (int q = 0; q < 5; ++q) ua[q] = Uq[(rr+2)*5 + q];
      }
      float2 acc = make_float2(0.f, 0.f);
#pragma unroll
      for (int q = 0; q < 5; ++q) {
        cmac(acc, make_float2(ub[q].x, ub[q].y), v[2*q]);
        cmac(acc, make_float2(ub[q].z, ub[q].w), v[2*q+1]);
      }
      if (KERR) {
        int r1 = rr + 1;
        float sn, cs; sincosf(angb + k3*(float)(r1*r1), &sn, &cs);
        acc = make_float2(acc.x*cs - acc.y*sn, acc.x*sn + acc.y*cs);
      }
      base[(rr+1)*sM] = acc;
    }
  }
}

// ------------------- K3: fused circuit — one block per batch, state in LDS -------------------
// LDS: state 88.8K + smU 25.6K + bsU(dbuf) 30.4K + misc ~0.6K = 145.4K < 160K
__global__ __launch_bounds__(1024) __attribute__((amdgpu_waves_per_eu(4, 4)))
void fused_circuit(
    const float2* __restrict__ slots, const void* __restrict__ w,
    const int* __restrict__ flag, float* __restrict__ out)
{
  __shared__ float2 st[ST_PHYS];                  // ~89 KB swizzled state
  __shared__ __align__(16) float2 smU[3200];      // all 32 single-mode U's
  __shared__ __align__(16) float2 bsU[3800];      // double-buffered BS gate
  __shared__ float2 psi[4][10];
  __shared__ float redw[64];
  const int b = blockIdx.x, t = threadIdx.x;
  const int wv = t >> 6, lane = t & 63;
  const int isf32 = *flag;

  const int ch0 = g_perm[wv][0], ch1 = g_perm[wv][1], ch2 = g_perm[wv][2];
  const bool smv = (t < 1000);
  const int q0 = t / 100, q1 = (t / 10) % 10, q2 = t % 10;

  // ---- initial product state ----
  if (t < 40) {
    int m = t / 10, r = t % 10;
    const float2* Dm = slots + (size_t)(SLOT_DM + b*4 + m) * 100;
    float2 acc = make_float2(0.f, 0.f);
    for (int c = 0; c < 10; ++c) {
      float2 a = Dm[r*10 + c];
      float2 vv = slots[(size_t)c * 10];   // S0 column 0
      acc.x += a.x*vv.x - a.y*vv.y;
      acc.y += a.x*vv.y + a.y*vv.x;
    }
    psi[m][r] = acc;
  }
  for (int i = t; i < 3200; i += 1024)
    smU[i] = slots[(size_t)SLOT_SQ * 100 + i];
  for (int i = t; i < 1900; i += 1024)
    bsU[i] = slots[(size_t)(SLOT_BS + 0) * 100 + i];
  __syncthreads();
  for (int e = t; e < 10000; e += 1024) {
    int ph = e + e/10 + e/100;
    float2 z  = psi[0][e/1000];
    float2 w1 = psi[1][(e/100)%10];
    float2 r1 = make_float2(z.x*w1.x - z.y*w1.y, z.x*w1.y + z.y*w1.x);
    float2 w2 = psi[2][(e/10)%10];
    float2 r2 = make_float2(r1.x*w2.x - r1.y*w2.y, r1.x*w2.y + r1.y*w2.x);
    float2 w3 = psi[3][e%10];
    st[ph] = make_float2(r2.x*w3.x - r2.y*w3.y, r2.x*w3.y + r2.y*w3.x);
  }
  __syncthreads();

  // split prefetch: global->reg at gate start, reg->LDS after compute.
  float2 pf0 = make_float2(0.f, 0.f), pf1 = make_float2(0.f, 0.f);
  auto pf_load = [&](int next) {
    if (next < 48) {
      const float2* src = slots + (size_t)(SLOT_BS + next*19) * 100;
      pf0 = src[t];
      if (t + 1024 < 1900) pf1 = src[t + 1024];
    }
  };
  auto pf_store = [&](int next) {
    if (next < 48) {
      float2* dst = bsU + (next & 1) * 1900;
      dst[t] = pf0;
      if (t + 1024 < 1900) dst[t + 1024] = pf1;
    }
  };

  // ---- circuit ----
#pragma unroll 1
  for (int l = 0; l < NLAYERS; ++l) {
#pragma unroll 1
    for (int half = 0; half < 2; ++half) {
      const int g6 = l*12 + half*6;
      int foff = l*WSTRIDE + (half ? 32 : 12);
      float f0 = readv(w, foff+0, isf32), f1 = readv(w, foff+1, isf32);
      float f2v = readv(w, foff+2, isf32), f3 = readv(w, foff+3, isf32);
      float fdc = f2v - f3;

      pf_load(g6+1);
      bs_gate<F0,F1,F2,F3,false>(st, bsU+((g6+0)&1)*1900, lane, ch0,ch1,ch2, 0,0,0,0);
      pf_store(g6+1);
      __syncthreads();
      pf_load(g6+2);
      bs_gate<F0,F2,F1,F3,false>(st, bsU+((g6+1)&1)*1900, lane, ch0,ch1,ch2, 0,0,0,0);
      pf_store(g6+2);
      __syncthreads();
      pf_load(g6+3);
      bs_gate<F0,F3,F1,F2,false>(st, bsU+((g6+2)&1)*1900, lane, ch0,ch1,ch2, 0,0,0,0);
      pf_store(g6+3);
      __syncthreads();
      pf_load(g6+4);
      bs_gate<F1,F2,F0,F3,false>(st, bsU+((g6+3)&1)*1900, lane, ch0,ch1,ch2, 0,0,0,0);
      pf_store(g6+4);
      __syncthreads();
      pf_load(g6+5);
      bs_gate<F1,F3,F0,F2,false>(st, bsU+((g6+4)&1)*1900, lane, ch0,ch1,ch2, 0,0,0,0);
      pf_store(g6+5);
      __syncthreads();
      pf_load(g6+6);
      bs_gate<F2,F3,F0,F1,true >(st, bsU+((g6+5)&1)*1900, lane, ch0,ch1,ch2, f0,f1,fdc,f3);
      pf_store(g6+6);
      __syncthreads();

      const int ub_ = (half == 0) ? (l*4) : (16 + l*4);
      float k0=0.f, k1=0.f, k2=0.f, k3=0.f;
      if (half == 1) {
        int koff = l*WSTRIDE + 44;
        k0 = readv(w, koff+0, isf32); k1 = readv(w, koff+1, isf32);
        k2 = readv(w, koff+2, isf32); k3 = readv(w, koff+3, isf32);
      }
      sm_gate<F0,F1,F2,F3,false>(st, smU+(ub_+0)*100, smv, q0,q1,q2, 0,0,0,0);
      __syncthreads();
      sm_gate<F1,F0,F2,F3,false>(st, smU+(ub_+1)*100, smv, q0,q1,q2, 0,0,0,0);
      __syncthreads();
      sm_gate<F2,F0,F1,F3,false>(st, smU+(ub_+2)*100, smv, q0,q1,q2, 0,0,0,0);
      __syncthreads();
      if (half == 1)
        sm_gate<F3,F0,F1,F2,true >(st, smU+(ub_+3)*100, smv, q0,q1,q2, k0,k1,k2,k3);
      else
        sm_gate<F3,F0,F1,F2,false>(st, smU+(ub_+3)*100, smv, q0,q1,q2, 0,0,0,0);
      __syncthreads();
    }
  }

  // ---- photon-number expectations (wave shuffle reduce) ----
  float a0 = 0.f, a1 = 0.f, a2 = 0.f, a3 = 0.f;
  for (int e = t; e < 10000; e += 1024) {
    int ph = e + e/10 + e/100;
    float2 z = st[ph];
    float pz = z.x*z.x + z.y*z.y;
    a0 += pz * (float)(e/1000);
    a1 += pz * (float)((e/100)%10);
    a2 += pz * (float)((e/10)%10);
    a3 += pz * (float)(e%10);
  }
  for (int off2 = 32; off2 > 0; off2 >>= 1) {
    a0 += __shfl_down(a0, off2, 64);
    a1 += __shfl_down(a1, off2, 64);
    a2 += __shfl_down(a2, off2, 64);
    a3 += __shfl_down(a3, off2, 64);
  }
  if (lane == 0) {
    redw[wv*4+0] = a0; redw[wv*4+1] = a1;
    redw[wv*4+2] = a2; redw[wv*4+3] = a3;
  }
  __syncthreads();
  if (t < 4) {
    float s = 0.f;
    for (int ww = 0; ww < 16; ++ww) s += redw[ww*4 + t];
    out[b*4 + t] = s;
  }
}

extern "C" void kernel_launch(void* const* d_in, const int* in_sizes, int n_in,
                              void* d_out, int out_size, void* d_ws, size_t ws_size,
                              hipStream_t stream) {
  const void* inp = d_in[0];
  const void* w   = d_in[1];
  float* out = (float*)d_out;           // reference output dtype is float32
  int*    flag  = (int*)d_ws;           // 16-byte header
  float2* slots = (float2*)((char*)d_ws + 16);

  sniff_dtype<<<dim3(1), dim3(256), 0, stream>>>(inp, in_sizes[0], flag);
  build_gens<<<dim3(NSLOTS), dim3(128), 0, stream>>>(slots, inp, w, flag);
  expm_all<<<dim3(NSLOTS), dim3(128), 0, stream>>>(slots);
  fused_circuit<<<dim3(NB), dim3(1024), 0, stream>>>(slots, w, flag, out);
}

// Round 11
// 418.279 us; speedup vs baseline: 2.2353x; 1.0047x over previous
//
#include <hip/hip_runtime.h>
#include <hip/hip_bf16.h>

#define CUT 10
#define NB 256
#define NLAYERS 4
#define WSTRIDE 48

// slot map (each slot = padded 10x10 complex, 100 float2)
#define SLOT_S0 0
#define SLOT_DM 1      // 1024 displacement-prep matrices
#define SLOT_SQ 1025   // 16 squeezers (l*4+m)
#define SLOT_DS 1041   // 16 displacements (l*4+m)
#define SLOT_BS 1057   // 48 gates * 19 photon-number blocks
#define NSLOTS  1969

typedef __hip_bfloat16 bf16;

// physical (bank-swizzled) per-mode strides: ph = 1110*n0 + 111*n1 + 11*n2 + n3
#define F0 1110
#define F1 111
#define F2 11
#define F3 1
#define ST_PHYS 11100

// read element i of a buffer whose dtype (f32 vs bf16) was sniffed at runtime
__device__ __forceinline__ float readv(const void* p, int i, int isf32) {
  if (isf32) return ((const float*)p)[i];
  return __bfloat162float(((const bf16*)p)[i]);
}

// packed complex MAC: acc += u * v using 2x v_pk_fma_f32 (vs 4x v_fma_f32)
__device__ __forceinline__ void cmac(float2& a, float2 u, float2 v) {
  asm("v_pk_fma_f32 %0, %1, %2, %0 op_sel:[0,0,0] op_sel_hi:[0,1,1]\n\t"
      "v_pk_fma_f32 %0, %1, %2, %0 op_sel:[1,1,0] op_sel_hi:[1,0,1] neg_lo:[1,0,0]"
      : "+v"(a) : "v"(u), "v"(v));
}

// chunk permutation: wave w handles chunks g_perm[w][0..2]; chunk c: N=c/2,
// spec offset (c&1)*64. Balanced so per-wave sum(d^2) is ~84 (range 76..100).
__device__ const signed char g_perm[16][3] = {
  {18,-1,-1},{19,-1,-1},{16, 0,-1},{17, 1,-1},{20,36,-1},{21,37,-1},
  {14, 6,34},{15, 7,35},{22,30,-1},{23,31,-1},{12, 8, 4},{13, 9, 5},
  {24,28,32},{25,29,33},{10,26, 2},{11,27, 3}
};

// ------------------- K0: sniff input dtype -------------------
__global__ void sniff_dtype(const void* p, int n_elems, int* flag) {
  __shared__ float red[256];
  const unsigned short* h = (const unsigned short*)p;
  int t = threadIdx.x;
  float mx = 0.f;
  for (int i = t; i < n_elems; i += 256) {
    unsigned short u = h[i];
    bf16 bv = *(const bf16*)&u;
    float v = fabsf(__bfloat162float(bv));
    if (!(v < 1e30f)) v = 1e30f;
    mx = fmaxf(mx, v);
  }
  red[t] = mx;
  __syncthreads();
  for (int off = 128; off > 0; off >>= 1) {
    if (t < off) red[t] = fmaxf(red[t], red[t + off]);
    __syncthreads();
  }
  if (t == 0) *flag = (red[0] > 1000.f) ? 1 : 0;  // 1 => buffer is really f32
}

// ------------------- K1: build all generators -------------------
__global__ void build_gens(float2* slots, const void* inp, const void* w,
                           const int* flag) {
  int s = blockIdx.x;
  int t = threadIdx.x;
  if (t >= 100) return;
  int isf32 = *flag;
  int i = t / 10, j = t % 10;
  float2 val = make_float2(0.f, 0.f);
  if (s == SLOT_S0) {
    if (j == i + 2)      { float c = sqrtf((float)((i+1)*(i+2))); val.y = -0.25f*c; }
    else if (i == j + 2) { float c = sqrtf((float)((j+1)*(j+2))); val.y = -0.25f*c; }
  } else if (s < SLOT_SQ) {
    int k = s - SLOT_DM;
    float r = readv(inp, k, isf32);
    if (i == j + 1)      val.x =  r * sqrtf((float)(j+1));
    else if (j == i + 1) val.x = -r * sqrtf((float)(i+1));
  } else if (s < SLOT_DS) {
    int k = s - SLOT_SQ; int l = k >> 2; int m = k & 3;
    float r = readv(w, l*WSTRIDE + 16 + m, isf32);
    if (j == i + 2)      val.x =  0.5f*r*sqrtf((float)((i+1)*(i+2)));
    else if (i == j + 2) val.x = -0.5f*r*sqrtf((float)((j+1)*(j+2)));
  } else if (s < SLOT_BS) {
    int k = s - SLOT_DS; int l = k >> 2; int m = k & 3;
    float rd = readv(w, l*WSTRIDE + 36 + m, isf32);
    float ph = readv(w, l*WSTRIDE + 40 + m, isf32);
    float ar = rd * cosf(ph), ai = rd * sinf(ph);
    if (i == j + 1)      { float c = sqrtf((float)(j+1)); val.x =  ar*c; val.y = ai*c; }
    else if (j == i + 1) { float c = sqrtf((float)(i+1)); val.x = -ar*c; val.y = ai*c; }
  } else {
    int rel = s - SLOT_BS;
    int g = rel / 19; int N = rel % 19;
    int l = g / 12; int h = (g % 12) / 6; int p = g % 6;
    float th = readv(w, l*WSTRIDE + (h ? 20 : 0) + p, isf32);
    float ph = readv(w, l*WSTRIDE + (h ? 26 : 6) + p, isf32);
    int lo = max(0, N - 9), hi = min(9, N);
    int d = hi - lo + 1;
    if (i < d && j < d) {
      if (i == j + 1) {
        float c = sqrtf((float)((lo + j + 1) * (N - lo - j)));
        val.x = th * cosf(ph) * c; val.y = th * sinf(ph) * c;
      } else if (j == i + 1) {
        float c = sqrtf((float)((lo + i + 1) * (N - lo - i)));
        val.x = -th * cosf(ph) * c; val.y = th * sinf(ph) * c;
      }
    }
  }
  slots[(size_t)s * 100 + t] = val;
}

// ------------------- K2: generic expm (scaling-squaring + Taylor) -------------------
__global__ void expm_all(float2* slots) {
  __shared__ float2 T[100], P[100], R[100];
  __shared__ float rowsum[10];
  __shared__ int sshift;
  int s = blockIdx.x, t = threadIdx.x;
  int i = t / 10, j = t % 10;
  float2* G = slots + (size_t)s * 100;
  if (t < 100) T[t] = G[t];
  __syncthreads();
  if (t < 10) {
    float sum = 0.f;
    for (int c = 0; c < 10; ++c) { float2 z = T[t*10+c]; sum += fabsf(z.x) + fabsf(z.y); }
    rowsum[t] = sum;
  }
  __syncthreads();
  if (t == 0) {
    float nm = 0.f;
    for (int r = 0; r < 10; ++r) nm = fmaxf(nm, rowsum[r]);
    int sc = 0;
    if (!(nm < 1e6f)) sc = 0;
    else if (nm > 0.25f) sc = (int)ceilf(log2f(nm * 4.f));
    sshift = min(max(sc, 0), 40);
  }
  __syncthreads();
  int sh = sshift;
  float scl = ldexpf(1.f, -sh);
  if (t < 100) {
    float2 z = T[t]; z.x *= scl; z.y *= scl;
    T[t] = z; P[t] = z;
    R[t] = make_float2(z.x + (i == j ? 1.f : 0.f), z.y);
  }
  __syncthreads();
  for (int k = 2; k <= 12; ++k) {
    float2 acc = make_float2(0.f, 0.f);
    if (t < 100) {
      for (int c = 0; c < 10; ++c) {
        float2 a = P[i*10+c], b = T[c*10+j];
        acc.x += a.x*b.x - a.y*b.y;
        acc.y += a.x*b.y + a.y*b.x;
      }
      float inv = 1.f / (float)k;
      acc.x *= inv; acc.y *= inv;
    }
    __syncthreads();
    if (t < 100) { P[t] = acc; R[t].x += acc.x; R[t].y += acc.y; }
    __syncthreads();
  }
  for (int q = 0; q < sh; ++q) {
    float2 acc = make_float2(0.f, 0.f);
    if (t < 100) {
      for (int c = 0; c < 10; ++c) {
        float2 a = R[i*10+c], b = R[c*10+j];
        acc.x += a.x*b.x - a.y*b.y;
        acc.y += a.x*b.y + a.y*b.x;
      }
    }
    __syncthreads();
    if (t < 100) R[t] = acc;
    __syncthreads();
  }
  if (t < 100) G[t] = R[t];
}

// ---- one BS line: row ping-pong (load row rr+1's U quads while computing rr) ----
template<int sI, int sJ, int sA, int sB, bool FUSE>
__device__ __forceinline__ void bs_chunk(
    float2* st, const float2* __restrict__ U, int sd,
    int hi10, int lo10, int lo, int N, float angb, float fdc)
{
  constexpr int step = sI - sJ;
  float2* base = st + hi10*sA + lo10*sB + lo*sI + (N - lo)*sJ;
  float2 v[10];
#pragma unroll
  for (int k = 0; k < 10; ++k) if (k < sd) v[k] = base[k*step];
  const float4* Uq = (const float4*)U;   // row rr -> quads [rr*5 .. rr*5+4]
  float4 ua[5], ub[5];
#pragma unroll
  for (int q = 0; q < 5; ++q) if (2*q < sd) ua[q] = Uq[q];
#pragma unroll
  for (int rr = 0; rr < 10; rr += 2) {
    if (rr < sd) {
      if (rr + 1 < sd) {
#pragma unroll
        for (int q = 0; q < 5; ++q) if (2*q < sd) ub[q] = Uq[(rr+1)*5 + q];
      }
      float2 acc = make_float2(0.f, 0.f);
#pragma unroll
      for (int q = 0; q < 5; ++q) if (2*q < sd) {
        cmac(acc, make_float2(ua[q].x, ua[q].y), v[2*q]);
        if (2*q + 1 < sd) cmac(acc, make_float2(ua[q].z, ua[q].w), v[2*q+1]);
      }
      if (FUSE) {
        float sn, cs; sincosf(angb + fdc*(float)rr, &sn, &cs);
        acc = make_float2(acc.x*cs - acc.y*sn, acc.x*sn + acc.y*cs);
      }
      base[rr*step] = acc;
    }
    if (rr + 1 < sd) {
      if (rr + 2 < sd) {
#pragma unroll
        for (int q = 0; q < 5; ++q) if (2*q < sd) ua[q] = Uq[(rr+2)*5 + q];
      }
      float2 acc = make_float2(0.f, 0.f);
#pragma unroll
      for (int q = 0; q < 5; ++q) if (2*q < sd) {
        cmac(acc, make_float2(ub[q].x, ub[q].y), v[2*q]);
        if (2*q + 1 < sd) cmac(acc, make_float2(ub[q].z, ub[q].w), v[2*q+1]);
      }
      if (FUSE) {
        float sn, cs; sincosf(angb + fdc*(float)(rr+1), &sn, &cs);
        acc = make_float2(acc.x*cs - acc.y*sn, acc.x*sn + acc.y*cs);
      }
      base[(rr+1)*step] = acc;
    }
  }
}

template<int sI, int sJ, int sA, int sB, bool FUSE>
__device__ __forceinline__ void bs_gate(
    float2* st, const float2* __restrict__ Ub, int lane,
    int ch0, int ch1, int ch2,
    float f0, float f1, float fdc, float f3)
{
#pragma unroll
  for (int r = 0; r < 3; ++r) {
    const int c = (r == 0) ? ch0 : (r == 1) ? ch1 : ch2;
    if (c >= 0) {
      int N = c >> 1;
      int spec = ((c & 1) << 6) + lane;
      if (spec < 100) {
        int lo = max(0, N - 9);
        const int sd = __builtin_amdgcn_readfirstlane(min(9, N) - lo + 1);
        int hi10 = spec / 10, lo10 = spec % 10;
        float angb = 0.f;
        if (FUSE)
          angb = f0*(float)hi10 + f1*(float)lo10 + f3*(float)N + fdc*(float)lo;
        bs_chunk<sI,sJ,sA,sB,FUSE>(st, Ub + N*100, sd, hi10, lo10, lo, N, angb, fdc);
      }
    }
  }
}

// ---- single-mode gate body: row ping-pong, full d=10 ----
template<int sM, int pA, int pB, int pC, bool KERR>
__device__ __forceinline__ void sm_gate(
    float2* st, const float2* __restrict__ U,
    bool smv, int q0, int q1, int q2,
    float k0, float k1, float k2, float k3)
{
  if (!smv) return;
  float2* base = st + q0*pA + q1*pB + q2*pC;
  float angb = 0.f;
  if (KERR) angb = k0*(float)(q0*q0) + k1*(float)(q1*q1) + k2*(float)(q2*q2);
  float2 v[10];
#pragma unroll
  for (int k = 0; k < 10; ++k) v[k] = base[k*sM];
  const float4* Uq = (const float4*)U;
  float4 ua[5], ub[5];
#pragma unroll
  for (int q = 0; q < 5; ++q) ua[q] = Uq[q];
#pragma unroll
  for (int rr = 0; rr < 10; rr += 2) {
    {
      if (rr + 1 < 10) {
#pragma unroll
        for (int q = 0; q < 5; ++q) ub[q] = Uq[(rr+1)*5 + q];
      }
      float2 acc = make_float2(0.f, 0.f);
#pragma unroll
      for (int q = 0; q < 5; ++q) {
        cmac(acc, make_float2(ua[q].x, ua[q].y), v[2*q]);
        cmac(acc, make_float2(ua[q].z, ua[q].w), v[2*q+1]);
      }
      if (KERR) {
        float sn, cs; sincosf(angb + k3*(float)(rr*rr), &sn, &cs);
        acc = make_float2(acc.x*cs - acc.y*sn, acc.x*sn + acc.y*cs);
      }
      base[rr*sM] = acc;
    }
    {
      if (rr + 2 < 10) {
#pragma unroll
        for (int q = 0; q < 5; ++q) ua[q] = Uq[(rr+2)*5 + q];
      }
      float2 acc = make_float2(0.f, 0.f);
#pragma unroll
      for (int q = 0; q < 5; ++q) {
        cmac(acc, make_float2(ub[q].x, ub[q].y), v[2*q]);
        cmac(acc, make_float2(ub[q].z, ub[q].w), v[2*q+1]);
      }
      if (KERR) {
        int r1 = rr + 1;
        float sn, cs; sincosf(angb + k3*(float)(r1*r1), &sn, &cs);
        acc = make_float2(acc.x*cs - acc.y*sn, acc.x*sn + acc.y*cs);
      }
      base[(rr+1)*sM] = acc;
    }
  }
}

// ------------------- K3: fused circuit — one block per batch, state in LDS -------------------
// LDS: state 88.8K + smU 25.6K + bsU(dbuf) 30.4K + misc ~0.6K = 145.4K < 160K
// __launch_bounds__(1024, 4): 4 waves/EU min -> VGPR cap 128 (not the default-8's 64).
// LDS already forces 1 block/CU, so this costs no occupancy.
__global__ __launch_bounds__(1024, 4)
void fused_circuit(
    const float2* __restrict__ slots, const void* __restrict__ w,
    const int* __restrict__ flag, float* __restrict__ out)
{
  __shared__ float2 st[ST_PHYS];                  // ~89 KB swizzled state
  __shared__ __align__(16) float2 smU[3200];      // all 32 single-mode U's
  __shared__ __align__(16) float2 bsU[3800];      // double-buffered BS gate
  __shared__ float2 psi[4][10];
  __shared__ float redw[64];
  const int b = blockIdx.x, t = threadIdx.x;
  const int wv = t >> 6, lane = t & 63;
  const int isf32 = *flag;

  const int ch0 = g_perm[wv][0], ch1 = g_perm[wv][1], ch2 = g_perm[wv][2];
  const bool smv = (t < 1000);
  const int q0 = t / 100, q1 = (t / 10) % 10, q2 = t % 10;

  // ---- initial product state ----
  if (t < 40) {
    int m = t / 10, r = t % 10;
    const float2* Dm = slots + (size_t)(SLOT_DM + b*4 + m) * 100;
    float2 acc = make_float2(0.f, 0.f);
    for (int c = 0; c < 10; ++c) {
      float2 a = Dm[r*10 + c];
      float2 vv = slots[(size_t)c * 10];   // S0 column 0
      acc.x += a.x*vv.x - a.y*vv.y;
      acc.y += a.x*vv.y + a.y*vv.x;
    }
    psi[m][r] = acc;
  }
  for (int i = t; i < 3200; i += 1024)
    smU[i] = slots[(size_t)SLOT_SQ * 100 + i];
  for (int i = t; i < 1900; i += 1024)
    bsU[i] = slots[(size_t)(SLOT_BS + 0) * 100 + i];
  __syncthreads();
  for (int e = t; e < 10000; e += 1024) {
    int ph = e + e/10 + e/100;
    float2 z  = psi[0][e/1000];
    float2 w1 = psi[1][(e/100)%10];
    float2 r1 = make_float2(z.x*w1.x - z.y*w1.y, z.x*w1.y + z.y*w1.x);
    float2 w2 = psi[2][(e/10)%10];
    float2 r2 = make_float2(r1.x*w2.x - r1.y*w2.y, r1.x*w2.y + r1.y*w2.x);
    float2 w3 = psi[3][e%10];
    st[ph] = make_float2(r2.x*w3.x - r2.y*w3.y, r2.x*w3.y + r2.y*w3.x);
  }
  __syncthreads();

  // split prefetch: global->reg at gate start, reg->LDS after compute.
  float2 pf0 = make_float2(0.f, 0.f), pf1 = make_float2(0.f, 0.f);
  auto pf_load = [&](int next) {
    if (next < 48) {
      const float2* src = slots + (size_t)(SLOT_BS + next*19) * 100;
      pf0 = src[t];
      if (t + 1024 < 1900) pf1 = src[t + 1024];
    }
  };
  auto pf_store = [&](int next) {
    if (next < 48) {
      float2* dst = bsU + (next & 1) * 1900;
      dst[t] = pf0;
      if (t + 1024 < 1900) dst[t + 1024] = pf1;
    }
  };

  // ---- circuit ----
#pragma unroll 1
  for (int l = 0; l < NLAYERS; ++l) {
#pragma unroll 1
    for (int half = 0; half < 2; ++half) {
      const int g6 = l*12 + half*6;
      int foff = l*WSTRIDE + (half ? 32 : 12);
      float f0 = readv(w, foff+0, isf32), f1 = readv(w, foff+1, isf32);
      float f2v = readv(w, foff+2, isf32), f3 = readv(w, foff+3, isf32);
      float fdc = f2v - f3;

      pf_load(g6+1);
      bs_gate<F0,F1,F2,F3,false>(st, bsU+((g6+0)&1)*1900, lane, ch0,ch1,ch2, 0,0,0,0);
      pf_store(g6+1);
      __syncthreads();
      pf_load(g6+2);
      bs_gate<F0,F2,F1,F3,false>(st, bsU+((g6+1)&1)*1900, lane, ch0,ch1,ch2, 0,0,0,0);
      pf_store(g6+2);
      __syncthreads();
      pf_load(g6+3);
      bs_gate<F0,F3,F1,F2,false>(st, bsU+((g6+2)&1)*1900, lane, ch0,ch1,ch2, 0,0,0,0);
      pf_store(g6+3);
      __syncthreads();
      pf_load(g6+4);
      bs_gate<F1,F2,F0,F3,false>(st, bsU+((g6+3)&1)*1900, lane, ch0,ch1,ch2, 0,0,0,0);
      pf_store(g6+4);
      __syncthreads();
      pf_load(g6+5);
      bs_gate<F1,F3,F0,F2,false>(st, bsU+((g6+4)&1)*1900, lane, ch0,ch1,ch2, 0,0,0,0);
      pf_store(g6+5);
      __syncthreads();
      pf_load(g6+6);
      bs_gate<F2,F3,F0,F1,true >(st, bsU+((g6+5)&1)*1900, lane, ch0,ch1,ch2, f0,f1,fdc,f3);
      pf_store(g6+6);
      __syncthreads();

      const int ub_ = (half == 0) ? (l*4) : (16 + l*4);
      float k0=0.f, k1=0.f, k2=0.f, k3=0.f;
      if (half == 1) {
        int koff = l*WSTRIDE + 44;
        k0 = readv(w, koff+0, isf32); k1 = readv(w, koff+1, isf32);
        k2 = readv(w, koff+2, isf32); k3 = readv(w, koff+3, isf32);
      }
      sm_gate<F0,F1,F2,F3,false>(st, smU+(ub_+0)*100, smv, q0,q1,q2, 0,0,0,0);
      __syncthreads();
      sm_gate<F1,F0,F2,F3,false>(st, smU+(ub_+1)*100, smv, q0,q1,q2, 0,0,0,0);
      __syncthreads();
      sm_gate<F2,F0,F1,F3,false>(st, smU+(ub_+2)*100, smv, q0,q1,q2, 0,0,0,0);
      __syncthreads();
      if (half == 1)
        sm_gate<F3,F0,F1,F2,true >(st, smU+(ub_+3)*100, smv, q0,q1,q2, k0,k1,k2,k3);
      else
        sm_gate<F3,F0,F1,F2,false>(st, smU+(ub_+3)*100, smv, q0,q1,q2, 0,0,0,0);
      __syncthreads();
    }
  }

  // ---- photon-number expectations (wave shuffle reduce) ----
  float a0 = 0.f, a1 = 0.f, a2 = 0.f, a3 = 0.f;
  for (int e = t; e < 10000; e += 1024) {
    int ph = e + e/10 + e/100;
    float2 z = st[ph];
    float pz = z.x*z.x + z.y*z.y;
    a0 += pz * (float)(e/1000);
    a1 += pz * (float)((e/100)%10);
    a2 += pz * (float)((e/10)%10);
    a3 += pz * (float)(e%10);
  }
  for (int off2 = 32; off2 > 0; off2 >>= 1) {
    a0 += __shfl_down(a0, off2, 64);
    a1 += __shfl_down(a1, off2, 64);
    a2 += __shfl_down(a2, off2, 64);
    a3 += __shfl_down(a3, off2, 64);
  }
  if (lane == 0) {
    redw[wv*4+0] = a0; redw[wv*4+1] = a1;
    redw[wv*4+2] = a2; redw[wv*4+3] = a3;
  }
  __syncthreads();
  if (t < 4) {
    float s = 0.f;
    for (int ww = 0; ww < 16; ++ww) s += redw[ww*4 + t];
    out[b*4 + t] = s;
  }
}

extern "C" void kernel_launch(void* const* d_in, const int* in_sizes, int n_in,
                              void* d_out, int out_size, void* d_ws, size_t ws_size,
                              hipStream_t stream) {
  const void* inp = d_in[0];
  const void* w   = d_in[1];
  float* out = (float*)d_out;           // reference output dtype is float32
  int*    flag  = (int*)d_ws;           // 16-byte header
  float2* slots = (float2*)((char*)d_ws + 16);

  sniff_dtype<<<dim3(1), dim3(256), 0, stream>>>(inp, in_sizes[0], flag);
  build_gens<<<dim3(NSLOTS), dim3(128), 0, stream>>>(slots, inp, w, flag);
  expm_all<<<dim3(NSLOTS), dim3(128), 0, stream>>>(slots);
  fused_circuit<<<dim3(NB), dim3(1024), 0, stream>>>(slots, w, flag, out);
}